// Round 8
// baseline (340.706 us; speedup 1.0000x reference)
//
#include <hip/hip_runtime.h>
#include <math.h>

#define B_ 4
#define S_ 2048
#define DM_ 1024
#define DK_ 128

static constexpr float SCALE = 0.08838834764831845f; // 1/sqrt(128)

__device__ __forceinline__ unsigned enc_f32(float f){
  unsigned u = __float_as_uint(f);
  return (u & 0x80000000u) ? ~u : (u | 0x80000000u);
}
__device__ __forceinline__ float dec_f32(unsigned u){
  unsigned v = (u & 0x80000000u) ? (u & 0x7FFFFFFFu) : ~u;
  return __uint_as_float(v);
}
__device__ __forceinline__ float f4get(const float4& v, int i){
  switch(i){ case 0: return v.x; case 1: return v.y; case 2: return v.z; default: return v.w; }
}

// ---- init: column-max to enc(-inf) ----
__global__ __launch_bounds__(256) void init_kernel(unsigned* __restrict__ cmax){
  int i = blockIdx.x*256 + threadIdx.x;
  if(i < B_*S_) cmax[i] = 0x007FFFFFu; // enc(-INF)
}

// ---- QKV GEMM v4: 32-row tiles + register double-buffer, launch_bounds(256,3) so the
//      prefetch state stays in VGPRs (round 4 spilled at the default occupancy target) ----
__global__ __launch_bounds__(256, 3) void qkv_kernel(
    const float* __restrict__ X, const float* __restrict__ Wq,
    const float* __restrict__ Wk, const float* __restrict__ Wv,
    float* __restrict__ Q, float* __restrict__ Kt, float* __restrict__ V)
{
  __shared__ __align__(16) float smem[32*68 + 64*128];  // Xs[32][68] + Ws[64][128]
  float* Xs = smem;
  float* Ws = smem + 32*68;
  const int tid = threadIdx.x;
  const int which = blockIdx.y;
  const float* Wm = (which==0) ? Wq : ((which==1) ? Wk : Wv);
  const int m0 = blockIdx.x * 32;
  const int tx = tid & 31, ty = tid >> 5;     // cols tx*4.., rows ty*4..
  const int xc_ = (tid & 15) << 2;            // X stage: rows tid>>4 (+32/256), col xc_
  const int wc_ = (tid & 31) << 2;            // W stage: rows tid>>5 (+8 each), col wc_
  float4 xpf[2], wpf[8];
  #pragma unroll
  for(int l=0;l<2;l++){
    int r = (tid + 256*l) >> 4;
    xpf[l] = *reinterpret_cast<const float4*>(&X[(size_t)(m0+r)*DM_ + xc_]);
  }
  #pragma unroll
  for(int l=0;l<8;l++){
    int r = (tid + 256*l) >> 5;
    wpf[l] = *reinterpret_cast<const float4*>(&Wm[(size_t)r*DK_ + wc_]);
  }
  float acc[4][4] = {};
  for(int k0 = 0; k0 < DM_; k0 += 64){
    __syncthreads();
    #pragma unroll
    for(int l=0;l<2;l++){
      int r = (tid + 256*l) >> 4;
      *reinterpret_cast<float4*>(&Xs[r*68 + xc_]) = xpf[l];
    }
    #pragma unroll
    for(int l=0;l<8;l++){
      int r = (tid + 256*l) >> 5;
      *reinterpret_cast<float4*>(&Ws[r*128 + wc_]) = wpf[l];
    }
    __syncthreads();
    if(k0 + 64 < DM_){                         // prefetch next k-tile into registers
      int kn = k0 + 64;
      #pragma unroll
      for(int l=0;l<2;l++){
        int r = (tid + 256*l) >> 4;
        xpf[l] = *reinterpret_cast<const float4*>(&X[(size_t)(m0+r)*DM_ + kn + xc_]);
      }
      #pragma unroll
      for(int l=0;l<8;l++){
        int r = (tid + 256*l) >> 5;
        wpf[l] = *reinterpret_cast<const float4*>(&Wm[(size_t)(kn+r)*DK_ + wc_]);
      }
    }
    #pragma unroll 4
    for(int kk=0;kk<64;kk+=4){
      float4 xr[4];
      #pragma unroll
      for(int i=0;i<4;i++) xr[i] = *reinterpret_cast<const float4*>(&Xs[(ty*4+i)*68 + kk]);
      #pragma unroll
      for(int k2=0;k2<4;k2++){
        float4 wv = *reinterpret_cast<const float4*>(&Ws[(kk+k2)*128 + tx*4]);
        #pragma unroll
        for(int i=0;i<4;i++){
          float xv = f4get(xr[i], k2);
          acc[i][0] = fmaf(xv, wv.x, acc[i][0]);
          acc[i][1] = fmaf(xv, wv.y, acc[i][1]);
          acc[i][2] = fmaf(xv, wv.z, acc[i][2]);
          acc[i][3] = fmaf(xv, wv.w, acc[i][3]);
        }
      }
    }
  }
  const int b = m0 >> 11;
  if(which != 1){
    float* O = (which==0) ? Q : V;
    #pragma unroll
    for(int i=0;i<4;i++){
      float4 v = {acc[i][0],acc[i][1],acc[i][2],acc[i][3]};
      *reinterpret_cast<float4*>(&O[(size_t)(m0 + ty*4 + i)*DK_ + tx*4]) = v;
    }
  } else {
    __syncthreads();
    float* Tmp = smem;                        // [32][133]
    #pragma unroll
    for(int i=0;i<4;i++)
      #pragma unroll
      for(int j=0;j<4;j++) Tmp[(ty*4+i)*133 + tx*4 + j] = acc[i][j];
    __syncthreads();
    const int s0 = m0 & (S_-1);
    #pragma unroll
    for(int l=0;l<16;l++){
      int p = tid + 256*l;                    // 4096 elems: 128 d x 32 r
      int d = p >> 5, r = p & 31;
      Kt[((size_t)(b*DK_ + d))*S_ + s0 + r] = Tmp[r*133 + d];
    }
  }
}

// ---- scores: raw s -> attn (upper tiles & masked entries = 0); column max ----
__global__ __launch_bounds__(256) void scores_kernel(
    const float* __restrict__ Q, const float* __restrict__ Kt,
    float* __restrict__ attn, unsigned* __restrict__ cmax)
{
  const int tj = blockIdx.x, ti = blockIdx.y, b = blockIdx.z;
  const int tid = threadIdx.x;
  const int q0 = ti*64, k0 = tj*64;
  if(tj > ti){                                 // upper triangle: zero-fill tile
    float4 z = {0.f,0.f,0.f,0.f};
    #pragma unroll
    for(int l=0;l<4;l++){
      int p = tid + 256*l;
      int r = p >> 4, c = (p & 15) << 2;
      *reinterpret_cast<float4*>(&attn[((size_t)(b*S_) + q0 + r)*S_ + k0 + c]) = z;
    }
    return;
  }
  __shared__ __align__(16) float Qs[64][132];
  __shared__ __align__(16) float Kst[128][68];
  __shared__ float cred[16][64];
  #pragma unroll
  for(int l=0;l<8;l++){                        // Q tile 64x128
    int p = tid + 256*l;
    int r = p >> 5, c = (p & 31) << 2;
    *reinterpret_cast<float4*>(&Qs[r][c]) =
      *reinterpret_cast<const float4*>(&Q[((size_t)(b*S_ + q0 + r))*DK_ + c]);
  }
  #pragma unroll
  for(int l=0;l<8;l++){                        // K^T tile 128x64
    int p = tid + 256*l;
    int d = p >> 4, c = (p & 15) << 2;
    *reinterpret_cast<float4*>(&Kst[d][c]) =
      *reinterpret_cast<const float4*>(&Kt[((size_t)(b*DK_ + d))*S_ + k0 + c]);
  }
  __syncthreads();
  const int tx = tid & 15, ty = tid >> 4;      // cols 4*tx.., rows 4*ty..
  float acc[4][4] = {};
  #pragma unroll 8
  for(int k=0;k<128;k++){
    float4 kv = *reinterpret_cast<const float4*>(&Kst[k][tx*4]);
    #pragma unroll
    for(int i=0;i<4;i++){
      float qv = Qs[ty*4+i][k];
      acc[i][0]=fmaf(qv,kv.x,acc[i][0]); acc[i][1]=fmaf(qv,kv.y,acc[i][1]);
      acc[i][2]=fmaf(qv,kv.z,acc[i][2]); acc[i][3]=fmaf(qv,kv.w,acc[i][3]);
    }
  }
  float cm[4] = {-INFINITY,-INFINITY,-INFINITY,-INFINITY};
  const bool full = (ti > tj);
  #pragma unroll
  for(int i=0;i<4;i++){
    int q = q0 + ty*4 + i;
    size_t base = ((size_t)(b*S_) + q)*S_ + k0 + tx*4;
    float s[4];
    #pragma unroll
    for(int j=0;j<4;j++) s[j] = acc[i][j]*SCALE;
    float4 v;
    bool v0 = full || (q >= k0 + tx*4 + 0);
    bool v1 = full || (q >= k0 + tx*4 + 1);
    bool v2 = full || (q >= k0 + tx*4 + 2);
    bool v3 = full || (q >= k0 + tx*4 + 3);
    v.x = v0 ? s[0] : 0.f;  v.y = v1 ? s[1] : 0.f;
    v.z = v2 ? s[2] : 0.f;  v.w = v3 ? s[3] : 0.f;
    *reinterpret_cast<float4*>(&attn[base]) = v;
    if(v0) cm[0]=fmaxf(cm[0],s[0]);
    if(v1) cm[1]=fmaxf(cm[1],s[1]);
    if(v2) cm[2]=fmaxf(cm[2],s[2]);
    if(v3) cm[3]=fmaxf(cm[3],s[3]);
  }
  #pragma unroll
  for(int j=0;j<4;j++) cred[ty][tx*4+j] = cm[j];
  __syncthreads();
  if(tid < 64){
    float m = cred[0][tid];
    #pragma unroll
    for(int g=1;g<16;g++) m = fmaxf(m, cred[g][tid]);
    atomicMax(&cmax[b*S_ + k0 + tid], enc_f32(m));
  }
}

// ---- exp + per-column partial sums, float4 in place ----
__global__ __launch_bounds__(256) void expsum_kernel(
    float* __restrict__ attn, const unsigned* __restrict__ cmax,
    float* __restrict__ colpart)
{
  const int cj = blockIdx.x, ti = blockIdx.y, b = blockIdx.z;
  if(ti < 4*cj) return;                        // fully masked block
  __shared__ float part[4][256];
  const int tid = threadIdx.x;
  const int c4 = tid & 63, g = tid >> 6;
  const int q0 = ti*64, k0 = cj*256;
  const int kbase = k0 + c4*4;
  float mc[4];
  #pragma unroll
  for(int j=0;j<4;j++) mc[j] = dec_f32(cmax[b*S_ + kbase + j]);
  float sum[4] = {0.f,0.f,0.f,0.f};
  #pragma unroll 4
  for(int rr=0;rr<16;rr++){
    int q = q0 + g*16 + rr;
    size_t idx = ((size_t)(b*S_) + q)*S_ + kbase;
    float4 sv = *reinterpret_cast<const float4*>(&attn[idx]);
    float4 ev;
    float e0 = __expf(sv.x - mc[0]);
    float e1 = __expf(sv.y - mc[1]);
    float e2 = __expf(sv.z - mc[2]);
    float e3 = __expf(sv.w - mc[3]);
    ev.x = (q >= kbase+0) ? e0 : 0.f;
    ev.y = (q >= kbase+1) ? e1 : 0.f;
    ev.z = (q >= kbase+2) ? e2 : 0.f;
    ev.w = (q >= kbase+3) ? e3 : 0.f;
    *reinterpret_cast<float4*>(&attn[idx]) = ev;
    sum[0]+=ev.x; sum[1]+=ev.y; sum[2]+=ev.z; sum[3]+=ev.w;
  }
  #pragma unroll
  for(int j=0;j<4;j++) part[g][c4*4+j] = sum[j];
  __syncthreads();
  {
    int k = k0 + tid;
    float tot = ((part[0][tid] + part[1][tid]) + part[2][tid]) + part[3][tid];
    colpart[((size_t)(b*S_) + k)*32 + ti] = tot;
  }
}

// ---- column reduce in fixed order -> reciprocal sums ----
__global__ __launch_bounds__(256) void colreduce_kernel(
    const float* __restrict__ colpart, float* __restrict__ rcol)
{
  int i = blockIdx.x*256 + threadIdx.x;  // 0..8191 = b*S + k
  if(i >= B_*S_) return;
  int k = i & (S_-1);
  int t0 = k >> 6;
  float s = 0.f;
  for(int t=t0; t<32; t++) s += colpart[(size_t)i*32 + t];
  rcol[i] = 1.0f / s;
}

// ---- scale V rows by rcol in place: V'[k,:] = V[k,:] * rcol[k] ----
__global__ __launch_bounds__(256) void vscale_kernel(
    float* __restrict__ V, const float* __restrict__ rcol)
{
  int i = blockIdx.x*256 + threadIdx.x;        // f4 index; 262144 total
  float4 v = reinterpret_cast<const float4*>(V)[i];
  float r = rcol[i >> 5];                      // 32 f4 per row; row == b*S + k
  v.x *= r; v.y *= r; v.z *= r; v.w *= r;
  reinterpret_cast<float4*>(V)[i] = v;
}

// ---- PV GEMM v3: 64x128 tile/block, V chunk in LDS, E broadcast from global ----
__global__ __launch_bounds__(256) void pv_kernel(
    const float* __restrict__ attn, const float* __restrict__ Vp,
    float* __restrict__ part, int ns)
{
  __shared__ __align__(16) float Vs[64][132];
  const int b = blockIdx.z, tid = threadIdx.x;
  const int sp = blockIdx.y;
  const int tx = tid & 31, ty = tid >> 5;          // cols tx*4.., rows ty+8j
  const int t = 31 - (int)blockIdx.x;              // heavy tiles first
  const int q0 = t*64;
  const int nch = t + 1;
  const int lo = (sp*nch)/ns, hi = ((sp+1)*nch)/ns;
  float acc[8][4] = {};
  const float* Arow = attn + ((size_t)(b*S_) + q0 + ty)*S_;   // rows ty+8j via +8j*S_
  for(int ch=lo; ch<hi; ++ch){
    const int k0 = ch*64;
    __syncthreads();
    #pragma unroll
    for(int l=0;l<8;l++){
      int p = tid + 256*l;
      int vr = p >> 5, vc = (p & 31) << 2;
      *reinterpret_cast<float4*>(&Vs[vr][vc]) =
        *reinterpret_cast<const float4*>(&Vp[((size_t)(b*S_) + k0 + vr)*DK_ + vc]);
    }
    __syncthreads();
    #pragma unroll 4
    for(int kk=0; kk<64; kk+=4){
      float4 e[8];
      #pragma unroll
      for(int j=0;j<8;j++)
        e[j] = *reinterpret_cast<const float4*>(&Arow[(size_t)(8*j)*S_ + k0 + kk]);
      #pragma unroll
      for(int k2=0;k2<4;k2++){
        float4 vv = *reinterpret_cast<const float4*>(&Vs[kk+k2][tx*4]);
        #pragma unroll
        for(int j=0;j<8;j++){
          float a = f4get(e[j],k2);
          acc[j][0]=fmaf(a,vv.x,acc[j][0]); acc[j][1]=fmaf(a,vv.y,acc[j][1]);
          acc[j][2]=fmaf(a,vv.z,acc[j][2]); acc[j][3]=fmaf(a,vv.w,acc[j][3]);
        }
      }
    }
  }
  float* pout = part + (((size_t)(sp*B_ + b))*S_ + q0)*DK_;   // 64 x 128 region
  #pragma unroll
  for(int j=0;j<8;j++){
    float4 o = {acc[j][0],acc[j][1],acc[j][2],acc[j][3]};
    *reinterpret_cast<float4*>(&pout[(size_t)(ty + 8*j)*DK_ + tx*4]) = o;
  }
}

// ---- sum split-K partials in fixed order ----
__global__ __launch_bounds__(256) void pvreduce_kernel(
    const float* __restrict__ part, float* __restrict__ out, int ns)
{
  const int N4 = (B_*S_*DK_)/4;   // 262144 float4
  int i = blockIdx.x*256 + threadIdx.x;
  if(i >= N4) return;
  const float4* p = reinterpret_cast<const float4*>(part);
  float4 a = p[i];
  for(int s=1; s<ns; ++s){
    float4 q = p[(size_t)s*N4 + i];
    a.x += q.x; a.y += q.y; a.z += q.z; a.w += q.w;
  }
  reinterpret_cast<float4*>(out)[i] = a;
}

// ---- normalize attention in place: attn[q,k] *= rcol[k] (lower-tri blocks only) ----
__global__ __launch_bounds__(256) void attnnorm_kernel(
    float* __restrict__ attn, const float* __restrict__ rcol)
{
  const int cj = blockIdx.x, ti = blockIdx.y, b = blockIdx.z;
  if(ti < 4*cj) return;                        // fully masked block: already zero
  const int tid = threadIdx.x;
  const int c4 = tid & 63, g = tid >> 6;
  const int q0 = ti*64, k0 = cj*256;
  const int kbase = k0 + c4*4;
  float4 r4 = *reinterpret_cast<const float4*>(&rcol[b*S_ + kbase]);
  #pragma unroll 4
  for(int rr=0;rr<16;rr++){
    int q = q0 + g*16 + rr;
    size_t idx = ((size_t)(b*S_) + q)*S_ + kbase;
    float4 e = *reinterpret_cast<const float4*>(&attn[idx]);
    e.x *= r4.x; e.y *= r4.y; e.z *= r4.z; e.w *= r4.w;
    *reinterpret_cast<float4*>(&attn[idx]) = e;
  }
}

extern "C" void kernel_launch(void* const* d_in, const int* in_sizes, int n_in,
                              void* d_out, int out_size, void* d_ws, size_t ws_size,
                              hipStream_t stream)
{
  (void)in_sizes; (void)n_in; (void)out_size;
  const float* X  = (const float*)d_in[0];
  const float* Wq = (const float*)d_in[1];
  const float* Wk = (const float*)d_in[2];
  const float* Wv = (const float*)d_in[3];
  float* out  = (float*)d_out;
  float* attn = out + (size_t)B_*S_*DK_;            // attention output region

  float* ws = (float*)d_ws;
  float* Q       = ws;                               // [4*2048*128]
  float* Kt      = ws + 1048576;                     // [4][128][2048]
  float* V       = ws + 2097152;                     // [4*2048*128]
  unsigned* cmax = (unsigned*)(ws + 3145728);        // [8192]
  float* rcol    = ws + 3145728 + 8192;              // [8192]
  float* colpart = ws + 3145728 + 16384;             // [8192][32]
  const size_t base = 3145728 + 16384 + 262144;      // floats used so far
  float* part    = ws + base;                        // [ns][4][2048][128]

  int ns = 4;
  if(ws_size < (base + (size_t)4*1048576)*sizeof(float)) ns = 2;
  if(ws_size < (base + (size_t)2*1048576)*sizeof(float)) ns = 1;

  init_kernel<<<dim3(32), dim3(256), 0, stream>>>(cmax);
  qkv_kernel<<<dim3(256,3), dim3(256), 0, stream>>>(X, Wq, Wk, Wv, Q, Kt, V);
  scores_kernel<<<dim3(32,32,4), dim3(256), 0, stream>>>(Q, Kt, attn, cmax);
  expsum_kernel<<<dim3(8,32,4), dim3(256), 0, stream>>>(attn, cmax, colpart);
  colreduce_kernel<<<dim3(32), dim3(256), 0, stream>>>(colpart, rcol);
  vscale_kernel<<<dim3(1024), dim3(256), 0, stream>>>(V, rcol);
  pv_kernel<<<dim3(32,ns,4), dim3(256), 0, stream>>>(attn, V, part, ns);
  pvreduce_kernel<<<dim3(1024), dim3(256), 0, stream>>>(part, out, ns);
  attnnorm_kernel<<<dim3(8,32,4), dim3(256), 0, stream>>>(attn, rcol);
}

// Round 9
// 285.492 us; speedup vs baseline: 1.1934x; 1.1934x over previous
//
#include <hip/hip_runtime.h>
#include <math.h>
#include <stdint.h>

#define B_ 4
#define S_ 2048
#define DM_ 1024
#define DK_ 128
#define QBK 32   // qkv K-tile

static constexpr float SCALE = 0.08838834764831845f; // 1/sqrt(128)

__device__ __forceinline__ unsigned enc_f32(float f){
  unsigned u = __float_as_uint(f);
  return (u & 0x80000000u) ? ~u : (u | 0x80000000u);
}
__device__ __forceinline__ float dec_f32(unsigned u){
  unsigned v = (u & 0x80000000u) ? (u & 0x7FFFFFFFu) : ~u;
  return __uint_as_float(v);
}
__device__ __forceinline__ float f4get(const float4& v, int i){
  switch(i){ case 0: return v.x; case 1: return v.y; case 2: return v.z; default: return v.w; }
}
// async global->LDS, 16B per lane; LDS dest = wave-uniform base + lane*16
__device__ __forceinline__ void gload16(const float* g, float* l){
  __builtin_amdgcn_global_load_lds(
      (const __attribute__((address_space(1))) void*)g,
      (__attribute__((address_space(3))) void*)l, 16, 0, 0);
}

// ---- init: column-max to enc(-inf) ----
__global__ __launch_bounds__(256) void init_kernel(unsigned* __restrict__ cmax){
  int i = blockIdx.x*256 + threadIdx.x;
  if(i < B_*S_) cmax[i] = 0x007FFFFFu; // enc(-INF)
}

// ---- QKV GEMM v5: global_load_lds double-buffer, linear LDS, zero register staging ----
__global__ __launch_bounds__(256) void qkv_kernel(
    const float* __restrict__ X, const float* __restrict__ Wq,
    const float* __restrict__ Wk, const float* __restrict__ Wv,
    float* __restrict__ Q, float* __restrict__ Kt, float* __restrict__ V)
{
  // per buffer: Xs[32][32] = 1024 f, Ws[32][128] = 4096 f  -> 5120 f; double-buffered.
  __shared__ __align__(16) float smem[2*5120];          // 40 KB
  const int tid = threadIdx.x;
  const int w = tid >> 6;                               // wave id 0..3
  const int lane = tid & 63;
  const int which = blockIdx.y;
  const float* Wm = (which==0) ? Wq : ((which==1) ? Wk : Wv);
  const int m0 = blockIdx.x * 32;
  const int tx = tid & 31, ty = tid >> 5;               // cols tx*4.., rows ty*4..

  // staging source pointers (per-lane global addresses)
  // X chunk (wave w): rows m0+8w .. m0+8w+7, 32 floats each
  const float* Xg = X + (size_t)(m0 + 8*w + (lane>>3))*DM_ + ((lane&7)<<2);
  // W tile rows k0..k0+31 are globally contiguous (128 f/row): chunk c = 1KB at c*256 f
  const float* Wg = Wm + (lane<<2);

  float acc[4][4] = {};
  int buf = 0;
  { // prologue: stage tile k0=0 into buf 0
    float* Xb = smem;
    float* Wb = smem + 1024;
    gload16(Xg, Xb + w*256);
    #pragma unroll
    for(int i=0;i<4;i++){
      int c = w + 4*i;
      gload16(Wg + (size_t)c*256, Wb + c*256);
    }
  }
  for(int k0 = 0; k0 < DM_; k0 += QBK){
    __syncthreads();                                    // drain vmcnt -> staged tile ready
    if(k0 + QBK < DM_){                                 // issue next tile (async, overlaps compute)
      float* Xb = smem + (buf^1)*5120;
      float* Wb = Xb + 1024;
      gload16(Xg + k0 + QBK, Xb + w*256);
      #pragma unroll
      for(int i=0;i<4;i++){
        int c = w + 4*i;
        gload16(Wg + (size_t)(k0+QBK)*DK_ + c*256, Wb + c*256);
      }
    }
    const float* Xb = smem + buf*5120;
    const float* Wb = Xb + 1024;
    #pragma unroll 8
    for(int kk=0;kk<QBK;kk+=4){
      float4 xr[4];
      #pragma unroll
      for(int i=0;i<4;i++)
        xr[i] = *reinterpret_cast<const float4*>(&Xb[(ty*4+i)*QBK + kk]);
      #pragma unroll
      for(int k2=0;k2<4;k2++){
        float4 wv = *reinterpret_cast<const float4*>(&Wb[(kk+k2)*128 + tx*4]);
        #pragma unroll
        for(int i=0;i<4;i++){
          float xv = f4get(xr[i], k2);
          acc[i][0] = fmaf(xv, wv.x, acc[i][0]);
          acc[i][1] = fmaf(xv, wv.y, acc[i][1]);
          acc[i][2] = fmaf(xv, wv.z, acc[i][2]);
          acc[i][3] = fmaf(xv, wv.w, acc[i][3]);
        }
      }
    }
    buf ^= 1;
  }
  const int b = m0 >> 11;
  if(which != 1){
    float* O = (which==0) ? Q : V;
    #pragma unroll
    for(int i=0;i<4;i++){
      float4 v = {acc[i][0],acc[i][1],acc[i][2],acc[i][3]};
      *reinterpret_cast<float4*>(&O[(size_t)(m0 + ty*4 + i)*DK_ + tx*4]) = v;
    }
  } else {
    __syncthreads();
    float* Tmp = smem;                        // [32][133]
    #pragma unroll
    for(int i=0;i<4;i++)
      #pragma unroll
      for(int j=0;j<4;j++) Tmp[(ty*4+i)*133 + tx*4 + j] = acc[i][j];
    __syncthreads();
    const int s0 = m0 & (S_-1);
    #pragma unroll
    for(int l=0;l<16;l++){
      int p = tid + 256*l;                    // 4096 elems: 128 d x 32 r
      int d = p >> 5, r = p & 31;
      Kt[((size_t)(b*DK_ + d))*S_ + s0 + r] = Tmp[r*133 + d];
    }
  }
}

// ---- scores: raw s -> attn (upper tiles & masked entries = 0); column max ----
__global__ __launch_bounds__(256) void scores_kernel(
    const float* __restrict__ Q, const float* __restrict__ Kt,
    float* __restrict__ attn, unsigned* __restrict__ cmax)
{
  const int tj = blockIdx.x, ti = blockIdx.y, b = blockIdx.z;
  const int tid = threadIdx.x;
  const int q0 = ti*64, k0 = tj*64;
  if(tj > ti){                                 // upper triangle: zero-fill tile
    float4 z = {0.f,0.f,0.f,0.f};
    #pragma unroll
    for(int l=0;l<4;l++){
      int p = tid + 256*l;
      int r = p >> 4, c = (p & 15) << 2;
      *reinterpret_cast<float4*>(&attn[((size_t)(b*S_) + q0 + r)*S_ + k0 + c]) = z;
    }
    return;
  }
  __shared__ __align__(16) float Qs[64][132];
  __shared__ __align__(16) float Kst[128][68];
  __shared__ float cred[16][64];
  #pragma unroll
  for(int l=0;l<8;l++){                        // Q tile 64x128
    int p = tid + 256*l;
    int r = p >> 5, c = (p & 31) << 2;
    *reinterpret_cast<float4*>(&Qs[r][c]) =
      *reinterpret_cast<const float4*>(&Q[((size_t)(b*S_ + q0 + r))*DK_ + c]);
  }
  #pragma unroll
  for(int l=0;l<8;l++){                        // K^T tile 128x64
    int p = tid + 256*l;
    int d = p >> 4, c = (p & 15) << 2;
    *reinterpret_cast<float4*>(&Kst[d][c]) =
      *reinterpret_cast<const float4*>(&Kt[((size_t)(b*DK_ + d))*S_ + k0 + c]);
  }
  __syncthreads();
  const int tx = tid & 15, ty = tid >> 4;      // cols 4*tx.., rows 4*ty..
  float acc[4][4] = {};
  #pragma unroll 8
  for(int k=0;k<128;k++){
    float4 kv = *reinterpret_cast<const float4*>(&Kst[k][tx*4]);
    #pragma unroll
    for(int i=0;i<4;i++){
      float qv = Qs[ty*4+i][k];
      acc[i][0]=fmaf(qv,kv.x,acc[i][0]); acc[i][1]=fmaf(qv,kv.y,acc[i][1]);
      acc[i][2]=fmaf(qv,kv.z,acc[i][2]); acc[i][3]=fmaf(qv,kv.w,acc[i][3]);
    }
  }
  float cm[4] = {-INFINITY,-INFINITY,-INFINITY,-INFINITY};
  const bool full = (ti > tj);
  #pragma unroll
  for(int i=0;i<4;i++){
    int q = q0 + ty*4 + i;
    size_t base = ((size_t)(b*S_) + q)*S_ + k0 + tx*4;
    float s[4];
    #pragma unroll
    for(int j=0;j<4;j++) s[j] = acc[i][j]*SCALE;
    float4 v;
    bool v0 = full || (q >= k0 + tx*4 + 0);
    bool v1 = full || (q >= k0 + tx*4 + 1);
    bool v2 = full || (q >= k0 + tx*4 + 2);
    bool v3 = full || (q >= k0 + tx*4 + 3);
    v.x = v0 ? s[0] : 0.f;  v.y = v1 ? s[1] : 0.f;
    v.z = v2 ? s[2] : 0.f;  v.w = v3 ? s[3] : 0.f;
    *reinterpret_cast<float4*>(&attn[base]) = v;
    if(v0) cm[0]=fmaxf(cm[0],s[0]);
    if(v1) cm[1]=fmaxf(cm[1],s[1]);
    if(v2) cm[2]=fmaxf(cm[2],s[2]);
    if(v3) cm[3]=fmaxf(cm[3],s[3]);
  }
  #pragma unroll
  for(int j=0;j<4;j++) cred[ty][tx*4+j] = cm[j];
  __syncthreads();
  if(tid < 64){
    float m = cred[0][tid];
    #pragma unroll
    for(int g=1;g<16;g++) m = fmaxf(m, cred[g][tid]);
    atomicMax(&cmax[b*S_ + k0 + tid], enc_f32(m));
  }
}

// ---- exp + per-column partial sums, float4 in place ----
__global__ __launch_bounds__(256) void expsum_kernel(
    float* __restrict__ attn, const unsigned* __restrict__ cmax,
    float* __restrict__ colpart)
{
  const int cj = blockIdx.x, ti = blockIdx.y, b = blockIdx.z;
  if(ti < 4*cj) return;                        // fully masked block
  __shared__ float part[4][256];
  const int tid = threadIdx.x;
  const int c4 = tid & 63, g = tid >> 6;
  const int q0 = ti*64, k0 = cj*256;
  const int kbase = k0 + c4*4;
  float mc[4];
  #pragma unroll
  for(int j=0;j<4;j++) mc[j] = dec_f32(cmax[b*S_ + kbase + j]);
  float sum[4] = {0.f,0.f,0.f,0.f};
  #pragma unroll 4
  for(int rr=0;rr<16;rr++){
    int q = q0 + g*16 + rr;
    size_t idx = ((size_t)(b*S_) + q)*S_ + kbase;
    float4 sv = *reinterpret_cast<const float4*>(&attn[idx]);
    float4 ev;
    float e0 = __expf(sv.x - mc[0]);
    float e1 = __expf(sv.y - mc[1]);
    float e2 = __expf(sv.z - mc[2]);
    float e3 = __expf(sv.w - mc[3]);
    ev.x = (q >= kbase+0) ? e0 : 0.f;
    ev.y = (q >= kbase+1) ? e1 : 0.f;
    ev.z = (q >= kbase+2) ? e2 : 0.f;
    ev.w = (q >= kbase+3) ? e3 : 0.f;
    *reinterpret_cast<float4*>(&attn[idx]) = ev;
    sum[0]+=ev.x; sum[1]+=ev.y; sum[2]+=ev.z; sum[3]+=ev.w;
  }
  #pragma unroll
  for(int j=0;j<4;j++) part[g][c4*4+j] = sum[j];
  __syncthreads();
  {
    int k = k0 + tid;
    float tot = ((part[0][tid] + part[1][tid]) + part[2][tid]) + part[3][tid];
    colpart[((size_t)(b*S_) + k)*32 + ti] = tot;
  }
}

// ---- column reduce in fixed order -> reciprocal sums ----
__global__ __launch_bounds__(256) void colreduce_kernel(
    const float* __restrict__ colpart, float* __restrict__ rcol)
{
  int i = blockIdx.x*256 + threadIdx.x;  // 0..8191 = b*S + k
  if(i >= B_*S_) return;
  int k = i & (S_-1);
  int t0 = k >> 6;
  float s = 0.f;
  for(int t=t0; t<32; t++) s += colpart[(size_t)i*32 + t];
  rcol[i] = 1.0f / s;
}

// ---- scale V rows by rcol in place: V'[k,:] = V[k,:] * rcol[k] ----
__global__ __launch_bounds__(256) void vscale_kernel(
    float* __restrict__ V, const float* __restrict__ rcol)
{
  int i = blockIdx.x*256 + threadIdx.x;        // f4 index; 262144 total
  float4 v = reinterpret_cast<const float4*>(V)[i];
  float r = rcol[i >> 5];                      // 32 f4 per row; row == b*S + k
  v.x *= r; v.y *= r; v.z *= r; v.w *= r;
  reinterpret_cast<float4*>(V)[i] = v;
}

// ---- PV GEMM v3: 64x128 tile/block, V chunk in LDS, E broadcast from global ----
__global__ __launch_bounds__(256) void pv_kernel(
    const float* __restrict__ attn, const float* __restrict__ Vp,
    float* __restrict__ part, int ns)
{
  __shared__ __align__(16) float Vs[64][132];
  const int b = blockIdx.z, tid = threadIdx.x;
  const int sp = blockIdx.y;
  const int tx = tid & 31, ty = tid >> 5;          // cols tx*4.., rows ty+8j
  const int t = 31 - (int)blockIdx.x;              // heavy tiles first
  const int q0 = t*64;
  const int nch = t + 1;
  const int lo = (sp*nch)/ns, hi = ((sp+1)*nch)/ns;
  float acc[8][4] = {};
  const float* Arow = attn + ((size_t)(b*S_) + q0 + ty)*S_;   // rows ty+8j via +8j*S_
  for(int ch=lo; ch<hi; ++ch){
    const int k0 = ch*64;
    __syncthreads();
    #pragma unroll
    for(int l=0;l<8;l++){
      int p = tid + 256*l;
      int vr = p >> 5, vc = (p & 31) << 2;
      *reinterpret_cast<float4*>(&Vs[vr][vc]) =
        *reinterpret_cast<const float4*>(&Vp[((size_t)(b*S_) + k0 + vr)*DK_ + vc]);
    }
    __syncthreads();
    #pragma unroll 4
    for(int kk=0; kk<64; kk+=4){
      float4 e[8];
      #pragma unroll
      for(int j=0;j<8;j++)
        e[j] = *reinterpret_cast<const float4*>(&Arow[(size_t)(8*j)*S_ + k0 + kk]);
      #pragma unroll
      for(int k2=0;k2<4;k2++){
        float4 vv = *reinterpret_cast<const float4*>(&Vs[kk+k2][tx*4]);
        #pragma unroll
        for(int j=0;j<8;j++){
          float a = f4get(e[j],k2);
          acc[j][0]=fmaf(a,vv.x,acc[j][0]); acc[j][1]=fmaf(a,vv.y,acc[j][1]);
          acc[j][2]=fmaf(a,vv.z,acc[j][2]); acc[j][3]=fmaf(a,vv.w,acc[j][3]);
        }
      }
    }
  }
  float* pout = part + (((size_t)(sp*B_ + b))*S_ + q0)*DK_;   // 64 x 128 region
  #pragma unroll
  for(int j=0;j<8;j++){
    float4 o = {acc[j][0],acc[j][1],acc[j][2],acc[j][3]};
    *reinterpret_cast<float4*>(&pout[(size_t)(ty + 8*j)*DK_ + tx*4]) = o;
  }
}

// ---- sum split-K partials in fixed order ----
__global__ __launch_bounds__(256) void pvreduce_kernel(
    const float* __restrict__ part, float* __restrict__ out, int ns)
{
  const int N4 = (B_*S_*DK_)/4;   // 262144 float4
  int i = blockIdx.x*256 + threadIdx.x;
  if(i >= N4) return;
  const float4* p = reinterpret_cast<const float4*>(part);
  float4 a = p[i];
  for(int s=1; s<ns; ++s){
    float4 q = p[(size_t)s*N4 + i];
    a.x += q.x; a.y += q.y; a.z += q.z; a.w += q.w;
  }
  reinterpret_cast<float4*>(out)[i] = a;
}

// ---- normalize attention in place: attn[q,k] *= rcol[k] (lower-tri blocks only) ----
__global__ __launch_bounds__(256) void attnnorm_kernel(
    float* __restrict__ attn, const float* __restrict__ rcol)
{
  const int cj = blockIdx.x, ti = blockIdx.y, b = blockIdx.z;
  if(ti < 4*cj) return;                        // fully masked block: already zero
  const int tid = threadIdx.x;
  const int c4 = tid & 63, g = tid >> 6;
  const int q0 = ti*64, k0 = cj*256;
  const int kbase = k0 + c4*4;
  float4 r4 = *reinterpret_cast<const float4*>(&rcol[b*S_ + kbase]);
  #pragma unroll 4
  for(int rr=0;rr<16;rr++){
    int q = q0 + g*16 + rr;
    size_t idx = ((size_t)(b*S_) + q)*S_ + kbase;
    float4 e = *reinterpret_cast<const float4*>(&attn[idx]);
    e.x *= r4.x; e.y *= r4.y; e.z *= r4.z; e.w *= r4.w;
    *reinterpret_cast<float4*>(&attn[idx]) = e;
  }
}

extern "C" void kernel_launch(void* const* d_in, const int* in_sizes, int n_in,
                              void* d_out, int out_size, void* d_ws, size_t ws_size,
                              hipStream_t stream)
{
  (void)in_sizes; (void)n_in; (void)out_size;
  const float* X  = (const float*)d_in[0];
  const float* Wq = (const float*)d_in[1];
  const float* Wk = (const float*)d_in[2];
  const float* Wv = (const float*)d_in[3];
  float* out  = (float*)d_out;
  float* attn = out + (size_t)B_*S_*DK_;            // attention output region

  float* ws = (float*)d_ws;
  float* Q       = ws;                               // [4*2048*128]
  float* Kt      = ws + 1048576;                     // [4][128][2048]
  float* V       = ws + 2097152;                     // [4*2048*128]
  unsigned* cmax = (unsigned*)(ws + 3145728);        // [8192]
  float* rcol    = ws + 3145728 + 8192;              // [8192]
  float* colpart = ws + 3145728 + 16384;             // [8192][32]
  const size_t base = 3145728 + 16384 + 262144;      // floats used so far
  float* part    = ws + base;                        // [ns][4][2048][128]

  int ns = 4;
  if(ws_size < (base + (size_t)4*1048576)*sizeof(float)) ns = 2;
  if(ws_size < (base + (size_t)2*1048576)*sizeof(float)) ns = 1;

  init_kernel<<<dim3(32), dim3(256), 0, stream>>>(cmax);
  qkv_kernel<<<dim3(256,3), dim3(256), 0, stream>>>(X, Wq, Wk, Wv, Q, Kt, V);
  scores_kernel<<<dim3(32,32,4), dim3(256), 0, stream>>>(Q, Kt, attn, cmax);
  expsum_kernel<<<dim3(8,32,4), dim3(256), 0, stream>>>(attn, cmax, colpart);
  colreduce_kernel<<<dim3(32), dim3(256), 0, stream>>>(colpart, rcol);
  vscale_kernel<<<dim3(1024), dim3(256), 0, stream>>>(V, rcol);
  pv_kernel<<<dim3(32,ns,4), dim3(256), 0, stream>>>(attn, V, part, ns);
  pvreduce_kernel<<<dim3(1024), dim3(256), 0, stream>>>(part, out, ns);
  attnnorm_kernel<<<dim3(8,32,4), dim3(256), 0, stream>>>(attn, rcol);
}

// Round 10
// 230.929 us; speedup vs baseline: 1.4754x; 1.2363x over previous
//
#include <hip/hip_runtime.h>
#include <math.h>
#include <stdint.h>

#define B_ 4
#define S_ 2048
#define DM_ 1024
#define DK_ 128

static constexpr float SCALE = 0.08838834764831845f; // 1/sqrt(128)

typedef __attribute__((ext_vector_type(8))) short short8;
typedef __attribute__((ext_vector_type(4))) float f32x4;
typedef __attribute__((ext_vector_type(4))) unsigned short us4;

__device__ __forceinline__ unsigned enc_f32(float f){
  unsigned u = __float_as_uint(f);
  return (u & 0x80000000u) ? ~u : (u | 0x80000000u);
}
__device__ __forceinline__ float dec_f32(unsigned u){
  unsigned v = (u & 0x80000000u) ? (u & 0x7FFFFFFFu) : ~u;
  return __uint_as_float(v);
}
__device__ __forceinline__ float f4get(const float4& v, int i){
  switch(i){ case 0: return v.x; case 1: return v.y; case 2: return v.z; default: return v.w; }
}
__device__ __forceinline__ unsigned short bf16rne(float f){
  unsigned u = __float_as_uint(f);
  unsigned r = (u + 0x7FFFu + ((u>>16)&1u)) >> 16;
  return (unsigned short)r;
}
__device__ __forceinline__ float bf16tof(unsigned short h){
  return __uint_as_float((unsigned)h << 16);
}
// async global->LDS, 16B per lane; LDS dest = wave-uniform base + lane*16
__device__ __forceinline__ void gload16(const void* g, void* l){
  __builtin_amdgcn_global_load_lds(
      (const __attribute__((address_space(1))) void*)g,
      (__attribute__((address_space(3))) void*)l, 16, 0, 0);
}

// ---- init: column-max to enc(-inf) ----
__global__ __launch_bounds__(256) void init_kernel(unsigned* __restrict__ cmax){
  int i = blockIdx.x*256 + threadIdx.x;
  if(i < B_*S_) cmax[i] = 0x007FFFFFu; // enc(-INF)
}

// ---- W pre-convert: f32 [1024][128] -> bf16 hi/lo, pre-tiled [32 t][col][40] (pad->bank-safe) ----
__global__ __launch_bounds__(256) void wconv_kernel(
    const float* __restrict__ Wq, const float* __restrict__ Wk, const float* __restrict__ Wv,
    unsigned short* __restrict__ Wth, unsigned short* __restrict__ Wtl)
{
  const int t = blockIdx.x;       // k-tile 0..31
  const int which = blockIdx.y;   // 0..2
  const float* W = (which==0) ? Wq : ((which==1) ? Wk : Wv);
  const int tid = threadIdx.x;
  const size_t obase = ((size_t)which*32 + t)*5120;
  #pragma unroll
  for(int it=0; it<2; ++it){
    int idx = tid + 256*it;       // 0..511 -> (col, g)
    int col = idx & 127, g = idx >> 7;
    unsigned short hs[8], ls[8];
    #pragma unroll
    for(int j=0;j<8;j++){
      float f = W[(size_t)(t*32 + g*8 + j)*DK_ + col];
      unsigned short h = bf16rne(f);
      hs[j] = h;
      ls[j] = bf16rne(f - bf16tof(h));
    }
    size_t o = obase + (size_t)col*40 + g*8;
    *(us4*)&Wth[o]   = us4{hs[0],hs[1],hs[2],hs[3]};
    *(us4*)&Wth[o+4] = us4{hs[4],hs[5],hs[6],hs[7]};
    *(us4*)&Wtl[o]   = us4{ls[0],ls[1],ls[2],ls[3]};
    *(us4*)&Wtl[o+4] = us4{ls[4],ls[5],ls[6],ls[7]};
  }
}

// ---- QKV GEMM v6: bf16x3 MFMA. M=32, BK=32; B hi/lo via global_load_lds dbuf;
//      X converted in-kernel (one float4 reg, no arrays -> no spill); A padded LDS. ----
__global__ __launch_bounds__(256) void qkv_mfma_kernel(
    const float* __restrict__ X,
    const unsigned short* __restrict__ Wth, const unsigned short* __restrict__ Wtl,
    float* __restrict__ Q, float* __restrict__ Kt, float* __restrict__ V)
{
  // carve: Ah[32][40] 2.5K | Al 2.5K | Bh0 10K | Bh1 10K | Bl0 10K | Bl1 10K = 45KB
  __shared__ __align__(16) unsigned char smem[46080];
  unsigned short* Ah = (unsigned short*)smem;
  unsigned short* Al = (unsigned short*)(smem + 2560);
  const int tid = threadIdx.x;
  const int w = tid >> 6, lane = tid & 63;
  const int which = blockIdx.y;
  const int m0 = blockIdx.x * 32;
  const unsigned char* Wh8 = (const unsigned char*)(Wth + (size_t)which*32*5120);
  const unsigned char* Wl8 = (const unsigned char*)(Wtl + (size_t)which*32*5120);

  // X register prefetch coords: thread -> (row, k-quad)
  const int xrow = tid >> 3, xkq = tid & 7;
  const float* Xg = X + (size_t)(m0 + xrow)*DM_ + xkq*4;
  float4 xv = *reinterpret_cast<const float4*>(Xg);     // tile 0

  // prologue: B tile 0 -> buf0 (20 x 1KB granule-gloads split across 4 waves)
  #pragma unroll
  for(int ii=0; ii<5; ++ii){
    int i = w + 4*ii;
    const unsigned char* src = (i<10) ? (Wh8 + i*1024) : (Wl8 + (i-10)*1024);
    unsigned dst = (i<10) ? (5120u + i*1024u) : (25600u + (unsigned)(i-10)*1024u);
    gload16(src + lane*16, smem + dst);
  }

  f32x4 acc[4] = {f32x4{0,0,0,0},f32x4{0,0,0,0},f32x4{0,0,0,0},f32x4{0,0,0,0}};
  const int r = w >> 1, c0 = (w & 1)*4;   // wave -> (row-tile, col-tile base)
  const int g = lane >> 4;
  const int aoff = (r*16 + (lane&15))*40 + g*8;
  int buf = 0;
  for(int t=0; t<32; ++t){
    __syncthreads();            // prev readers done; B gloads (cur buf) drained
    {  // write A tile t (hi/lo bf16) from the prefetched float4
      unsigned short h0=bf16rne(xv.x), h1=bf16rne(xv.y), h2=bf16rne(xv.z), h3=bf16rne(xv.w);
      us4 hs = {h0,h1,h2,h3};
      us4 ls = { bf16rne(xv.x - bf16tof(h0)), bf16rne(xv.y - bf16tof(h1)),
                 bf16rne(xv.z - bf16tof(h2)), bf16rne(xv.w - bf16tof(h3)) };
      *(us4*)&Ah[xrow*40 + xkq*4] = hs;
      *(us4*)&Al[xrow*40 + xkq*4] = ls;
    }
    __syncthreads();            // A visible
    if(t+1 < 32){               // issue next B tile (async; drains at next barrier) + X reg prefetch
      const unsigned char* WhT = Wh8 + (size_t)(t+1)*10240;
      const unsigned char* WlT = Wl8 + (size_t)(t+1)*10240;
      unsigned bhN = (buf^1) ? 15360u : 5120u;
      unsigned blN = (buf^1) ? 35840u : 25600u;
      #pragma unroll
      for(int ii=0; ii<5; ++ii){
        int i = w + 4*ii;
        const unsigned char* src = (i<10) ? (WhT + i*1024) : (WlT + (i-10)*1024);
        unsigned dst = (i<10) ? (bhN + i*1024) : (blN + (unsigned)(i-10)*1024);
        gload16(src + lane*16, smem + dst);
      }
      xv = *reinterpret_cast<const float4*>(Xg + (t+1)*32);
    }
    const unsigned short* Bhc = (const unsigned short*)(smem + (buf ? 15360 : 5120));
    const unsigned short* Blc = (const unsigned short*)(smem + (buf ? 35840 : 25600));
    short8 ah = *(const short8*)&Ah[aoff];
    short8 al = *(const short8*)&Al[aoff];
    #pragma unroll
    for(int c=0;c<4;c++){
      int boff = ((c0+c)*16 + (lane&15))*40 + g*8;
      short8 bh = *(const short8*)&Bhc[boff];
      short8 bl = *(const short8*)&Blc[boff];
      acc[c] = __builtin_amdgcn_mfma_f32_16x16x32_bf16(ah, bh, acc[c], 0, 0, 0);
      acc[c] = __builtin_amdgcn_mfma_f32_16x16x32_bf16(ah, bl, acc[c], 0, 0, 0);
      acc[c] = __builtin_amdgcn_mfma_f32_16x16x32_bf16(al, bh, acc[c], 0, 0, 0);
    }
    buf ^= 1;
  }
  // epilogue: C layout col=lane&15, row=(lane>>4)*4+reg  [verified m89/m91]
  const int b = m0 >> 11;
  const int orow0 = (lane>>4)*4;
  if(which != 1){
    float* O = (which==0) ? Q : V;
    #pragma unroll
    for(int c=0;c<4;c++){
      int col = (c0+c)*16 + (lane&15);
      #pragma unroll
      for(int j=0;j<4;j++)
        O[(size_t)(m0 + r*16 + orow0 + j)*DK_ + col] = acc[c][j];
    }
  } else {
    __syncthreads();
    float* Tmp = (float*)smem;                 // [32][133] = 17KB
    #pragma unroll
    for(int c=0;c<4;c++){
      int col = (c0+c)*16 + (lane&15);
      #pragma unroll
      for(int j=0;j<4;j++)
        Tmp[(r*16 + orow0 + j)*133 + col] = acc[c][j];
    }
    __syncthreads();
    const int s0 = m0 & (S_-1);
    #pragma unroll
    for(int l2=0;l2<16;l2++){
      int p = tid + 256*l2;                    // 4096 elems: 128 d x 32 r
      int d = p >> 5, rr = p & 31;
      Kt[((size_t)(b*DK_ + d))*S_ + s0 + rr] = Tmp[rr*133 + d];
    }
  }
}

// ---- scores: raw s -> attn (upper tiles & masked entries = 0); column max ----
__global__ __launch_bounds__(256) void scores_kernel(
    const float* __restrict__ Q, const float* __restrict__ Kt,
    float* __restrict__ attn, unsigned* __restrict__ cmax)
{
  const int tj = blockIdx.x, ti = blockIdx.y, b = blockIdx.z;
  const int tid = threadIdx.x;
  const int q0 = ti*64, k0 = tj*64;
  if(tj > ti){                                 // upper triangle: zero-fill tile
    float4 z = {0.f,0.f,0.f,0.f};
    #pragma unroll
    for(int l=0;l<4;l++){
      int p = tid + 256*l;
      int r = p >> 4, c = (p & 15) << 2;
      *reinterpret_cast<float4*>(&attn[((size_t)(b*S_) + q0 + r)*S_ + k0 + c]) = z;
    }
    return;
  }
  __shared__ __align__(16) float Qs[64][132];
  __shared__ __align__(16) float Kst[128][68];
  __shared__ float cred[16][64];
  #pragma unroll
  for(int l=0;l<8;l++){                        // Q tile 64x128
    int p = tid + 256*l;
    int r = p >> 5, c = (p & 31) << 2;
    *reinterpret_cast<float4*>(&Qs[r][c]) =
      *reinterpret_cast<const float4*>(&Q[((size_t)(b*S_ + q0 + r))*DK_ + c]);
  }
  #pragma unroll
  for(int l=0;l<8;l++){                        // K^T tile 128x64
    int p = tid + 256*l;
    int d = p >> 4, c = (p & 15) << 2;
    *reinterpret_cast<float4*>(&Kst[d][c]) =
      *reinterpret_cast<const float4*>(&Kt[((size_t)(b*DK_ + d))*S_ + k0 + c]);
  }
  __syncthreads();
  const int tx = tid & 15, ty = tid >> 4;      // cols 4*tx.., rows 4*ty..
  float acc[4][4] = {};
  #pragma unroll 8
  for(int k=0;k<128;k++){
    float4 kv = *reinterpret_cast<const float4*>(&Kst[k][tx*4]);
    #pragma unroll
    for(int i=0;i<4;i++){
      float qv = Qs[ty*4+i][k];
      acc[i][0]=fmaf(qv,kv.x,acc[i][0]); acc[i][1]=fmaf(qv,kv.y,acc[i][1]);
      acc[i][2]=fmaf(qv,kv.z,acc[i][2]); acc[i][3]=fmaf(qv,kv.w,acc[i][3]);
    }
  }
  float cm[4] = {-INFINITY,-INFINITY,-INFINITY,-INFINITY};
  const bool full = (ti > tj);
  #pragma unroll
  for(int i=0;i<4;i++){
    int q = q0 + ty*4 + i;
    size_t base = ((size_t)(b*S_) + q)*S_ + k0 + tx*4;
    float s[4];
    #pragma unroll
    for(int j=0;j<4;j++) s[j] = acc[i][j]*SCALE;
    float4 v;
    bool v0 = full || (q >= k0 + tx*4 + 0);
    bool v1 = full || (q >= k0 + tx*4 + 1);
    bool v2 = full || (q >= k0 + tx*4 + 2);
    bool v3 = full || (q >= k0 + tx*4 + 3);
    v.x = v0 ? s[0] : 0.f;  v.y = v1 ? s[1] : 0.f;
    v.z = v2 ? s[2] : 0.f;  v.w = v3 ? s[3] : 0.f;
    *reinterpret_cast<float4*>(&attn[base]) = v;
    if(v0) cm[0]=fmaxf(cm[0],s[0]);
    if(v1) cm[1]=fmaxf(cm[1],s[1]);
    if(v2) cm[2]=fmaxf(cm[2],s[2]);
    if(v3) cm[3]=fmaxf(cm[3],s[3]);
  }
  #pragma unroll
  for(int j=0;j<4;j++) cred[ty][tx*4+j] = cm[j];
  __syncthreads();
  if(tid < 64){
    float m = cred[0][tid];
    #pragma unroll
    for(int g=1;g<16;g++) m = fmaxf(m, cred[g][tid]);
    atomicMax(&cmax[b*S_ + k0 + tid], enc_f32(m));
  }
}

// ---- exp + per-column partial sums, float4 in place ----
__global__ __launch_bounds__(256) void expsum_kernel(
    float* __restrict__ attn, const unsigned* __restrict__ cmax,
    float* __restrict__ colpart)
{
  const int cj = blockIdx.x, ti = blockIdx.y, b = blockIdx.z;
  if(ti < 4*cj) return;                        // fully masked block
  __shared__ float part[4][256];
  const int tid = threadIdx.x;
  const int c4 = tid & 63, g = tid >> 6;
  const int q0 = ti*64, k0 = cj*256;
  const int kbase = k0 + c4*4;
  float mc[4];
  #pragma unroll
  for(int j=0;j<4;j++) mc[j] = dec_f32(cmax[b*S_ + kbase + j]);
  float sum[4] = {0.f,0.f,0.f,0.f};
  #pragma unroll 4
  for(int rr=0;rr<16;rr++){
    int q = q0 + g*16 + rr;
    size_t idx = ((size_t)(b*S_) + q)*S_ + kbase;
    float4 sv = *reinterpret_cast<const float4*>(&attn[idx]);
    float4 ev;
    float e0 = __expf(sv.x - mc[0]);
    float e1 = __expf(sv.y - mc[1]);
    float e2 = __expf(sv.z - mc[2]);
    float e3 = __expf(sv.w - mc[3]);
    ev.x = (q >= kbase+0) ? e0 : 0.f;
    ev.y = (q >= kbase+1) ? e1 : 0.f;
    ev.z = (q >= kbase+2) ? e2 : 0.f;
    ev.w = (q >= kbase+3) ? e3 : 0.f;
    *reinterpret_cast<float4*>(&attn[idx]) = ev;
    sum[0]+=ev.x; sum[1]+=ev.y; sum[2]+=ev.z; sum[3]+=ev.w;
  }
  #pragma unroll
  for(int j=0;j<4;j++) part[g][c4*4+j] = sum[j];
  __syncthreads();
  {
    int k = k0 + tid;
    float tot = ((part[0][tid] + part[1][tid]) + part[2][tid]) + part[3][tid];
    colpart[((size_t)(b*S_) + k)*32 + ti] = tot;
  }
}

// ---- column reduce in fixed order -> reciprocal sums ----
__global__ __launch_bounds__(256) void colreduce_kernel(
    const float* __restrict__ colpart, float* __restrict__ rcol)
{
  int i = blockIdx.x*256 + threadIdx.x;  // 0..8191 = b*S + k
  if(i >= B_*S_) return;
  int k = i & (S_-1);
  int t0 = k >> 6;
  float s = 0.f;
  for(int t=t0; t<32; t++) s += colpart[(size_t)i*32 + t];
  rcol[i] = 1.0f / s;
}

// ---- scale V rows by rcol in place: V'[k,:] = V[k,:] * rcol[k] ----
__global__ __launch_bounds__(256) void vscale_kernel(
    float* __restrict__ V, const float* __restrict__ rcol)
{
  int i = blockIdx.x*256 + threadIdx.x;        // f4 index; 262144 total
  float4 v = reinterpret_cast<const float4*>(V)[i];
  float r = rcol[i >> 5];                      // 32 f4 per row; row == b*S + k
  v.x *= r; v.y *= r; v.z *= r; v.w *= r;
  reinterpret_cast<float4*>(V)[i] = v;
}

// ---- PV GEMM: 64x128 tile/block, V chunk in LDS, E broadcast from global ----
__global__ __launch_bounds__(256) void pv_kernel(
    const float* __restrict__ attn, const float* __restrict__ Vp,
    float* __restrict__ part, int ns)
{
  __shared__ __align__(16) float Vs[64][132];
  const int b = blockIdx.z, tid = threadIdx.x;
  const int sp = blockIdx.y;
  const int tx = tid & 31, ty = tid >> 5;          // cols tx*4.., rows ty+8j
  const int t = 31 - (int)blockIdx.x;              // heavy tiles first
  const int q0 = t*64;
  const int nch = t + 1;
  const int lo = (sp*nch)/ns, hi = ((sp+1)*nch)/ns;
  float acc[8][4] = {};
  const float* Arow = attn + ((size_t)(b*S_) + q0 + ty)*S_;   // rows ty+8j via +8j*S_
  for(int ch=lo; ch<hi; ++ch){
    const int k0 = ch*64;
    __syncthreads();
    #pragma unroll
    for(int l=0;l<8;l++){
      int p = tid + 256*l;
      int vr = p >> 5, vc = (p & 31) << 2;
      *reinterpret_cast<float4*>(&Vs[vr][vc]) =
        *reinterpret_cast<const float4*>(&Vp[((size_t)(b*S_) + k0 + vr)*DK_ + vc]);
    }
    __syncthreads();
    #pragma unroll 4
    for(int kk=0; kk<64; kk+=4){
      float4 e[8];
      #pragma unroll
      for(int j=0;j<8;j++)
        e[j] = *reinterpret_cast<const float4*>(&Arow[(size_t)(8*j)*S_ + k0 + kk]);
      #pragma unroll
      for(int k2=0;k2<4;k2++){
        float4 vv = *reinterpret_cast<const float4*>(&Vs[kk+k2][tx*4]);
        #pragma unroll
        for(int j=0;j<8;j++){
          float a = f4get(e[j],k2);
          acc[j][0]=fmaf(a,vv.x,acc[j][0]); acc[j][1]=fmaf(a,vv.y,acc[j][1]);
          acc[j][2]=fmaf(a,vv.z,acc[j][2]); acc[j][3]=fmaf(a,vv.w,acc[j][3]);
        }
      }
    }
  }
  float* pout = part + (((size_t)(sp*B_ + b))*S_ + q0)*DK_;   // 64 x 128 region
  #pragma unroll
  for(int j=0;j<8;j++){
    float4 o = {acc[j][0],acc[j][1],acc[j][2],acc[j][3]};
    *reinterpret_cast<float4*>(&pout[(size_t)(ty + 8*j)*DK_ + tx*4]) = o;
  }
}

// ---- sum split-K partials in fixed order ----
__global__ __launch_bounds__(256) void pvreduce_kernel(
    const float* __restrict__ part, float* __restrict__ out, int ns)
{
  const int N4 = (B_*S_*DK_)/4;   // 262144 float4
  int i = blockIdx.x*256 + threadIdx.x;
  if(i >= N4) return;
  const float4* p = reinterpret_cast<const float4*>(part);
  float4 a = p[i];
  for(int s=1; s<ns; ++s){
    float4 q = p[(size_t)s*N4 + i];
    a.x += q.x; a.y += q.y; a.z += q.z; a.w += q.w;
  }
  reinterpret_cast<float4*>(out)[i] = a;
}

// ---- normalize attention in place: attn[q,k] *= rcol[k] (lower-tri blocks only) ----
__global__ __launch_bounds__(256) void attnnorm_kernel(
    float* __restrict__ attn, const float* __restrict__ rcol)
{
  const int cj = blockIdx.x, ti = blockIdx.y, b = blockIdx.z;
  if(ti < 4*cj) return;                        // fully masked block: already zero
  const int tid = threadIdx.x;
  const int c4 = tid & 63, g = tid >> 6;
  const int q0 = ti*64, k0 = cj*256;
  const int kbase = k0 + c4*4;
  float4 r4 = *reinterpret_cast<const float4*>(&rcol[b*S_ + kbase]);
  #pragma unroll 4
  for(int rr=0;rr<16;rr++){
    int q = q0 + g*16 + rr;
    size_t idx = ((size_t)(b*S_) + q)*S_ + kbase;
    float4 e = *reinterpret_cast<const float4*>(&attn[idx]);
    e.x *= r4.x; e.y *= r4.y; e.z *= r4.z; e.w *= r4.w;
    *reinterpret_cast<float4*>(&attn[idx]) = e;
  }
}

extern "C" void kernel_launch(void* const* d_in, const int* in_sizes, int n_in,
                              void* d_out, int out_size, void* d_ws, size_t ws_size,
                              hipStream_t stream)
{
  (void)in_sizes; (void)n_in; (void)out_size;
  const float* X  = (const float*)d_in[0];
  const float* Wq = (const float*)d_in[1];
  const float* Wk = (const float*)d_in[2];
  const float* Wv = (const float*)d_in[3];
  float* out  = (float*)d_out;
  float* attn = out + (size_t)B_*S_*DK_;            // attention output region

  float* ws = (float*)d_ws;
  float* Q       = ws;                               // [4*2048*128]
  float* Kt      = ws + 1048576;                     // [4][128][2048]
  float* V       = ws + 2097152;                     // [4*2048*128]
  unsigned* cmax = (unsigned*)(ws + 3145728);        // [8192]
  float* rcol    = ws + 3145728 + 8192;              // [8192]
  float* colpart = ws + 3145728 + 16384;             // [8192][32]
  unsigned short* Wth = (unsigned short*)(ws + 3424256);        // [3][32][5120] bf16
  unsigned short* Wtl = Wth + (size_t)3*32*5120;                // same
  const size_t base = 3424256 + 245760 + 245760;     // floats used so far (3915776)
  float* part    = ws + base;                        // [ns][4][2048][128]

  int ns = 4;
  if(ws_size < (base + (size_t)4*1048576)*sizeof(float)) ns = 2;
  if(ws_size < (base + (size_t)2*1048576)*sizeof(float)) ns = 1;

  init_kernel<<<dim3(32), dim3(256), 0, stream>>>(cmax);
  wconv_kernel<<<dim3(32,3), dim3(256), 0, stream>>>(Wq, Wk, Wv, Wth, Wtl);
  qkv_mfma_kernel<<<dim3(256,3), dim3(256), 0, stream>>>(X, Wth, Wtl, Q, Kt, V);
  scores_kernel<<<dim3(32,32,4), dim3(256), 0, stream>>>(Q, Kt, attn, cmax);
  expsum_kernel<<<dim3(8,32,4), dim3(256), 0, stream>>>(attn, cmax, colpart);
  colreduce_kernel<<<dim3(32), dim3(256), 0, stream>>>(colpart, rcol);
  vscale_kernel<<<dim3(1024), dim3(256), 0, stream>>>(V, rcol);
  pv_kernel<<<dim3(32,ns,4), dim3(256), 0, stream>>>(attn, V, part, ns);
  pvreduce_kernel<<<dim3(1024), dim3(256), 0, stream>>>(part, out, ns);
  attnnorm_kernel<<<dim3(8,32,4), dim3(256), 0, stream>>>(attn, rcol);
}

// Round 11
// 202.000 us; speedup vs baseline: 1.6867x; 1.1432x over previous
//
#include <hip/hip_runtime.h>
#include <math.h>
#include <stdint.h>

#define B_ 4
#define S_ 2048
#define DM_ 1024
#define DK_ 128

static constexpr float SCALE = 0.08838834764831845f; // 1/sqrt(128)

typedef __attribute__((ext_vector_type(8))) short short8;
typedef __attribute__((ext_vector_type(4))) float f32x4;
typedef __attribute__((ext_vector_type(4))) unsigned short us4;

__device__ __forceinline__ unsigned enc_f32(float f){
  unsigned u = __float_as_uint(f);
  return (u & 0x80000000u) ? ~u : (u | 0x80000000u);
}
__device__ __forceinline__ float dec_f32(unsigned u){
  unsigned v = (u & 0x80000000u) ? (u & 0x7FFFFFFFu) : ~u;
  return __uint_as_float(v);
}
__device__ __forceinline__ float f4get(const float4& v, int i){
  switch(i){ case 0: return v.x; case 1: return v.y; case 2: return v.z; default: return v.w; }
}
__device__ __forceinline__ unsigned short bf16rne(float f){
  unsigned u = __float_as_uint(f);
  unsigned r = (u + 0x7FFFu + ((u>>16)&1u)) >> 16;
  return (unsigned short)r;
}
__device__ __forceinline__ float bf16tof(unsigned short h){
  return __uint_as_float((unsigned)h << 16);
}
// async global->LDS, 16B per lane; LDS dest = wave-uniform base + lane*16
__device__ __forceinline__ void gload16(const void* g, void* l){
  __builtin_amdgcn_global_load_lds(
      (const __attribute__((address_space(1))) void*)g,
      (__attribute__((address_space(3))) void*)l, 16, 0, 0);
}

// ---- init: column-max to enc(-inf) ----
__global__ __launch_bounds__(256) void init_kernel(unsigned* __restrict__ cmax){
  int i = blockIdx.x*256 + threadIdx.x;
  if(i < B_*S_) cmax[i] = 0x007FFFFFu; // enc(-INF)
}

// ---- W pre-convert: f32 [1024][128] -> bf16 hi/lo, pre-tiled [32 t][col][40] ----
__global__ __launch_bounds__(256) void wconv_kernel(
    const float* __restrict__ Wq, const float* __restrict__ Wk, const float* __restrict__ Wv,
    unsigned short* __restrict__ Wth, unsigned short* __restrict__ Wtl)
{
  const int t = blockIdx.x;       // k-tile 0..31
  const int which = blockIdx.y;   // 0..2
  const float* W = (which==0) ? Wq : ((which==1) ? Wk : Wv);
  const int tid = threadIdx.x;
  const size_t obase = ((size_t)which*32 + t)*5120;
  #pragma unroll
  for(int it=0; it<2; ++it){
    int idx = tid + 256*it;       // 0..511 -> (col, g)
    int col = idx & 127, g = idx >> 7;
    unsigned short hs[8], ls[8];
    #pragma unroll
    for(int j=0;j<8;j++){
      float f = W[(size_t)(t*32 + g*8 + j)*DK_ + col];
      unsigned short h = bf16rne(f);
      hs[j] = h;
      ls[j] = bf16rne(f - bf16tof(h));
    }
    size_t o = obase + (size_t)col*40 + g*8;
    *(us4*)&Wth[o]   = us4{hs[0],hs[1],hs[2],hs[3]};
    *(us4*)&Wth[o+4] = us4{hs[4],hs[5],hs[6],hs[7]};
    *(us4*)&Wtl[o]   = us4{ls[0],ls[1],ls[2],ls[3]};
    *(us4*)&Wtl[o+4] = us4{ls[4],ls[5],ls[6],ls[7]};
  }
}

// ---- QKV GEMM: bf16x3 MFMA. Q,K written as bf16 hi/lo (dense [8192][128]); V f32 ----
__global__ __launch_bounds__(256) void qkv_mfma_kernel(
    const float* __restrict__ X,
    const unsigned short* __restrict__ Wth, const unsigned short* __restrict__ Wtl,
    unsigned short* __restrict__ Qh, unsigned short* __restrict__ Ql,
    unsigned short* __restrict__ Kh, unsigned short* __restrict__ Kl,
    float* __restrict__ V)
{
  // carve: Ah[32][40] 2.5K | Al 2.5K | Bh0 10K | Bh1 10K | Bl0 10K | Bl1 10K = 45KB
  __shared__ __align__(16) unsigned char smem[46080];
  unsigned short* Ah = (unsigned short*)smem;
  unsigned short* Al = (unsigned short*)(smem + 2560);
  const int tid = threadIdx.x;
  const int w = tid >> 6, lane = tid & 63;
  const int which = blockIdx.y;
  const int m0 = blockIdx.x * 32;
  const unsigned char* Wh8 = (const unsigned char*)(Wth + (size_t)which*32*5120);
  const unsigned char* Wl8 = (const unsigned char*)(Wtl + (size_t)which*32*5120);

  // X register prefetch coords: thread -> (row, k-quad)
  const int xrow = tid >> 3, xkq = tid & 7;
  const float* Xg = X + (size_t)(m0 + xrow)*DM_ + xkq*4;
  float4 xv = *reinterpret_cast<const float4*>(Xg);     // tile 0

  // prologue: B tile 0 -> buf0
  #pragma unroll
  for(int ii=0; ii<5; ++ii){
    int i = w + 4*ii;
    const unsigned char* src = (i<10) ? (Wh8 + i*1024) : (Wl8 + (i-10)*1024);
    unsigned dst = (i<10) ? (5120u + i*1024u) : (25600u + (unsigned)(i-10)*1024u);
    gload16(src + lane*16, smem + dst);
  }

  f32x4 acc[4] = {f32x4{0,0,0,0},f32x4{0,0,0,0},f32x4{0,0,0,0},f32x4{0,0,0,0}};
  const int r = w >> 1, c0 = (w & 1)*4;   // wave -> (row-tile, col-tile base)
  const int g = lane >> 4;
  const int aoff = (r*16 + (lane&15))*40 + g*8;
  int buf = 0;
  for(int t=0; t<32; ++t){
    __syncthreads();            // prev readers done; B gloads (cur buf) drained
    {  // write A tile t (hi/lo bf16) from the prefetched float4
      unsigned short h0=bf16rne(xv.x), h1=bf16rne(xv.y), h2=bf16rne(xv.z), h3=bf16rne(xv.w);
      us4 hs = {h0,h1,h2,h3};
      us4 ls = { bf16rne(xv.x - bf16tof(h0)), bf16rne(xv.y - bf16tof(h1)),
                 bf16rne(xv.z - bf16tof(h2)), bf16rne(xv.w - bf16tof(h3)) };
      *(us4*)&Ah[xrow*40 + xkq*4] = hs;
      *(us4*)&Al[xrow*40 + xkq*4] = ls;
    }
    __syncthreads();            // A visible
    if(t+1 < 32){               // issue next B tile + X reg prefetch
      const unsigned char* WhT = Wh8 + (size_t)(t+1)*10240;
      const unsigned char* WlT = Wl8 + (size_t)(t+1)*10240;
      unsigned bhN = (buf^1) ? 15360u : 5120u;
      unsigned blN = (buf^1) ? 35840u : 25600u;
      #pragma unroll
      for(int ii=0; ii<5; ++ii){
        int i = w + 4*ii;
        const unsigned char* src = (i<10) ? (WhT + i*1024) : (WlT + (i-10)*1024);
        unsigned dst = (i<10) ? (bhN + i*1024) : (blN + (unsigned)(i-10)*1024);
        gload16(src + lane*16, smem + dst);
      }
      xv = *reinterpret_cast<const float4*>(Xg + (t+1)*32);
    }
    const unsigned short* Bhc = (const unsigned short*)(smem + (buf ? 15360 : 5120));
    const unsigned short* Blc = (const unsigned short*)(smem + (buf ? 35840 : 25600));
    short8 ah = *(const short8*)&Ah[aoff];
    short8 al = *(const short8*)&Al[aoff];
    #pragma unroll
    for(int c=0;c<4;c++){
      int boff = ((c0+c)*16 + (lane&15))*40 + g*8;
      short8 bh = *(const short8*)&Bhc[boff];
      short8 bl = *(const short8*)&Blc[boff];
      acc[c] = __builtin_amdgcn_mfma_f32_16x16x32_bf16(ah, bh, acc[c], 0, 0, 0);
      acc[c] = __builtin_amdgcn_mfma_f32_16x16x32_bf16(ah, bl, acc[c], 0, 0, 0);
      acc[c] = __builtin_amdgcn_mfma_f32_16x16x32_bf16(al, bh, acc[c], 0, 0, 0);
    }
    buf ^= 1;
  }
  // epilogue: C layout col=lane&15, row=(lane>>4)*4+reg  [verified m89/m91]
  const int orow0 = (lane>>4)*4;
  if(which == 2){
    #pragma unroll
    for(int c=0;c<4;c++){
      int col = (c0+c)*16 + (lane&15);
      #pragma unroll
      for(int j=0;j<4;j++)
        V[(size_t)(m0 + r*16 + orow0 + j)*DK_ + col] = acc[c][j];
    }
  } else {
    unsigned short* Oh = (which==0) ? Qh : Kh;
    unsigned short* Ol = (which==0) ? Ql : Kl;
    #pragma unroll
    for(int c=0;c<4;c++){
      int col = (c0+c)*16 + (lane&15);
      #pragma unroll
      for(int j=0;j<4;j++){
        float f = acc[c][j];
        unsigned short h = bf16rne(f);
        unsigned short lo = bf16rne(f - bf16tof(h));
        size_t o = (size_t)(m0 + r*16 + orow0 + j)*DK_ + col;
        Oh[o] = h; Ol[o] = lo;
      }
    }
  }
}

// ---- scores via bf16x3 MFMA: S = Q K^T * scale; masked store + column max ----
__global__ __launch_bounds__(256) void scores_kernel(
    const unsigned short* __restrict__ Qh, const unsigned short* __restrict__ Ql,
    const unsigned short* __restrict__ Kh, const unsigned short* __restrict__ Kl,
    float* __restrict__ attn, unsigned* __restrict__ cmax)
{
  const int tj = blockIdx.x, ti = blockIdx.y, b = blockIdx.z;
  const int tid = threadIdx.x;
  const int q0 = ti*64, k0 = tj*64;
  if(tj > ti){                                 // upper triangle: zero-fill tile
    float4 z = {0.f,0.f,0.f,0.f};
    #pragma unroll
    for(int l=0;l<4;l++){
      int p = tid + 256*l;
      int r = p >> 4, c = (p & 15) << 2;
      *reinterpret_cast<float4*>(&attn[((size_t)(b*S_) + q0 + r)*S_ + k0 + c]) = z;
    }
    return;
  }
  __shared__ __align__(16) unsigned short sm[18432];   // 4 x [64][72] shorts = 36.8KB
  __shared__ float cred[16][64];
  unsigned short* Qhs = sm;
  unsigned short* Qls = sm + 4608;
  unsigned short* Khs = sm + 9216;
  unsigned short* Kls = sm + 13824;
  const int w = tid >> 6, lane = tid & 63, l15 = lane & 15, g = lane >> 4;
  f32x4 acc[4] = {f32x4{0,0,0,0},f32x4{0,0,0,0},f32x4{0,0,0,0},f32x4{0,0,0,0}};
  for(int kh=0; kh<2; ++kh){
    __syncthreads();                           // prev compute readers done
    #pragma unroll
    for(int l=0;l<2;l++){                      // stage 4 tiles (this K-half)
      int p = tid + 256*l;                     // 512 loads of 8 shorts per tile
      int row = p >> 3, cc = p & 7;
      size_t gq = (size_t)(b*S_ + q0 + row)*DK_ + kh*64 + cc*8;
      size_t gk = (size_t)(b*S_ + k0 + row)*DK_ + kh*64 + cc*8;
      int lo_ = row*72 + cc*8;
      *(short8*)&Qhs[lo_] = *(const short8*)&Qh[gq];
      *(short8*)&Qls[lo_] = *(const short8*)&Ql[gq];
      *(short8*)&Khs[lo_] = *(const short8*)&Kh[gk];
      *(short8*)&Kls[lo_] = *(const short8*)&Kl[gk];
    }
    __syncthreads();
    #pragma unroll
    for(int ks=0; ks<2; ++ks){                 // 2 x K=32 per half
      int ao = (w*16 + l15)*72 + ks*32 + g*8;
      short8 ah = *(const short8*)&Qhs[ao];
      short8 al = *(const short8*)&Qls[ao];
      #pragma unroll
      for(int c=0;c<4;c++){
        int bo = (c*16 + l15)*72 + ks*32 + g*8;
        short8 bh = *(const short8*)&Khs[bo];
        short8 bl = *(const short8*)&Kls[bo];
        acc[c] = __builtin_amdgcn_mfma_f32_16x16x32_bf16(ah, bh, acc[c], 0, 0, 0);
        acc[c] = __builtin_amdgcn_mfma_f32_16x16x32_bf16(ah, bl, acc[c], 0, 0, 0);
        acc[c] = __builtin_amdgcn_mfma_f32_16x16x32_bf16(al, bh, acc[c], 0, 0, 0);
      }
    }
  }
  // epilogue: scale, mask, store, column-max
  const bool full = (ti > tj);
  const int qbase = q0 + w*16 + g*4;
  #pragma unroll
  for(int c=0;c<4;c++){
    int kcol = k0 + c*16 + l15;
    float cm = -INFINITY;
    #pragma unroll
    for(int j=0;j<4;j++){
      int q = qbase + j;
      float s = acc[c][j]*SCALE;
      bool valid = full || (q >= kcol);
      attn[((size_t)(b*S_) + q)*S_ + kcol] = valid ? s : 0.f;
      if(valid) cm = fmaxf(cm, s);
    }
    cred[w*4 + g][c*16 + l15] = cm;
  }
  __syncthreads();
  if(tid < 64){
    float m = cred[0][tid];
    #pragma unroll
    for(int gg=1;gg<16;gg++) m = fmaxf(m, cred[gg][tid]);
    atomicMax(&cmax[b*S_ + k0 + tid], enc_f32(m));
  }
}

// ---- exp + per-column partial sums, float4 in place ----
__global__ __launch_bounds__(256) void expsum_kernel(
    float* __restrict__ attn, const unsigned* __restrict__ cmax,
    float* __restrict__ colpart)
{
  const int cj = blockIdx.x, ti = blockIdx.y, b = blockIdx.z;
  if(ti < 4*cj) return;                        // fully masked block
  __shared__ float part[4][256];
  const int tid = threadIdx.x;
  const int c4 = tid & 63, g = tid >> 6;
  const int q0 = ti*64, k0 = cj*256;
  const int kbase = k0 + c4*4;
  float mc[4];
  #pragma unroll
  for(int j=0;j<4;j++) mc[j] = dec_f32(cmax[b*S_ + kbase + j]);
  float sum[4] = {0.f,0.f,0.f,0.f};
  #pragma unroll 4
  for(int rr=0;rr<16;rr++){
    int q = q0 + g*16 + rr;
    size_t idx = ((size_t)(b*S_) + q)*S_ + kbase;
    float4 sv = *reinterpret_cast<const float4*>(&attn[idx]);
    float4 ev;
    float e0 = __expf(sv.x - mc[0]);
    float e1 = __expf(sv.y - mc[1]);
    float e2 = __expf(sv.z - mc[2]);
    float e3 = __expf(sv.w - mc[3]);
    ev.x = (q >= kbase+0) ? e0 : 0.f;
    ev.y = (q >= kbase+1) ? e1 : 0.f;
    ev.z = (q >= kbase+2) ? e2 : 0.f;
    ev.w = (q >= kbase+3) ? e3 : 0.f;
    *reinterpret_cast<float4*>(&attn[idx]) = ev;
    sum[0]+=ev.x; sum[1]+=ev.y; sum[2]+=ev.z; sum[3]+=ev.w;
  }
  #pragma unroll
  for(int j=0;j<4;j++) part[g][c4*4+j] = sum[j];
  __syncthreads();
  {
    int k = k0 + tid;
    float tot = ((part[0][tid] + part[1][tid]) + part[2][tid]) + part[3][tid];
    colpart[((size_t)(b*S_) + k)*32 + ti] = tot;
  }
}

// ---- column reduce in fixed order -> reciprocal sums ----
__global__ __launch_bounds__(256) void colreduce_kernel(
    const float* __restrict__ colpart, float* __restrict__ rcol)
{
  int i = blockIdx.x*256 + threadIdx.x;  // 0..8191 = b*S + k
  if(i >= B_*S_) return;
  int k = i & (S_-1);
  int t0 = k >> 6;
  float s = 0.f;
  for(int t=t0; t<32; t++) s += colpart[(size_t)i*32 + t];
  rcol[i] = 1.0f / s;
}

// ---- scale V rows by rcol in place: V'[k,:] = V[k,:] * rcol[k] ----
__global__ __launch_bounds__(256) void vscale_kernel(
    float* __restrict__ V, const float* __restrict__ rcol)
{
  int i = blockIdx.x*256 + threadIdx.x;        // f4 index; 262144 total
  float4 v = reinterpret_cast<const float4*>(V)[i];
  float r = rcol[i >> 5];                      // 32 f4 per row; row == b*S + k
  v.x *= r; v.y *= r; v.z *= r; v.w *= r;
  reinterpret_cast<float4*>(V)[i] = v;
}

// ---- PV GEMM: 64x128 tile/block, V chunk in LDS, E broadcast from global ----
__global__ __launch_bounds__(256) void pv_kernel(
    const float* __restrict__ attn, const float* __restrict__ Vp,
    float* __restrict__ part, int ns)
{
  __shared__ __align__(16) float Vs[64][132];
  const int b = blockIdx.z, tid = threadIdx.x;
  const int sp = blockIdx.y;
  const int tx = tid & 31, ty = tid >> 5;          // cols tx*4.., rows ty+8j
  const int t = 31 - (int)blockIdx.x;              // heavy tiles first
  const int q0 = t*64;
  const int nch = t + 1;
  const int lo = (sp*nch)/ns, hi = ((sp+1)*nch)/ns;
  float acc[8][4] = {};
  const float* Arow = attn + ((size_t)(b*S_) + q0 + ty)*S_;   // rows ty+8j via +8j*S_
  for(int ch=lo; ch<hi; ++ch){
    const int k0 = ch*64;
    __syncthreads();
    #pragma unroll
    for(int l=0;l<8;l++){
      int p = tid + 256*l;
      int vr = p >> 5, vc = (p & 31) << 2;
      *reinterpret_cast<float4*>(&Vs[vr][vc]) =
        *reinterpret_cast<const float4*>(&Vp[((size_t)(b*S_) + k0 + vr)*DK_ + vc]);
    }
    __syncthreads();
    #pragma unroll 4
    for(int kk=0; kk<64; kk+=4){
      float4 e[8];
      #pragma unroll
      for(int j=0;j<8;j++)
        e[j] = *reinterpret_cast<const float4*>(&Arow[(size_t)(8*j)*S_ + k0 + kk]);
      #pragma unroll
      for(int k2=0;k2<4;k2++){
        float4 vv = *reinterpret_cast<const float4*>(&Vs[kk+k2][tx*4]);
        #pragma unroll
        for(int j=0;j<8;j++){
          float a = f4get(e[j],k2);
          acc[j][0]=fmaf(a,vv.x,acc[j][0]); acc[j][1]=fmaf(a,vv.y,acc[j][1]);
          acc[j][2]=fmaf(a,vv.z,acc[j][2]); acc[j][3]=fmaf(a,vv.w,acc[j][3]);
        }
      }
    }
  }
  float* pout = part + (((size_t)(sp*B_ + b))*S_ + q0)*DK_;   // 64 x 128 region
  #pragma unroll
  for(int j=0;j<8;j++){
    float4 o = {acc[j][0],acc[j][1],acc[j][2],acc[j][3]};
    *reinterpret_cast<float4*>(&pout[(size_t)(ty + 8*j)*DK_ + tx*4]) = o;
  }
}

// ---- sum split-K partials in fixed order ----
__global__ __launch_bounds__(256) void pvreduce_kernel(
    const float* __restrict__ part, float* __restrict__ out, int ns)
{
  const int N4 = (B_*S_*DK_)/4;   // 262144 float4
  int i = blockIdx.x*256 + threadIdx.x;
  if(i >= N4) return;
  const float4* p = reinterpret_cast<const float4*>(part);
  float4 a = p[i];
  for(int s=1; s<ns; ++s){
    float4 q = p[(size_t)s*N4 + i];
    a.x += q.x; a.y += q.y; a.z += q.z; a.w += q.w;
  }
  reinterpret_cast<float4*>(out)[i] = a;
}

// ---- normalize attention in place: attn[q,k] *= rcol[k] (lower-tri blocks only) ----
__global__ __launch_bounds__(256) void attnnorm_kernel(
    float* __restrict__ attn, const float* __restrict__ rcol)
{
  const int cj = blockIdx.x, ti = blockIdx.y, b = blockIdx.z;
  if(ti < 4*cj) return;                        // fully masked block: already zero
  const int tid = threadIdx.x;
  const int c4 = tid & 63, g = tid >> 6;
  const int q0 = ti*64, k0 = cj*256;
  const int kbase = k0 + c4*4;
  float4 r4 = *reinterpret_cast<const float4*>(&rcol[b*S_ + kbase]);
  #pragma unroll 4
  for(int rr=0;rr<16;rr++){
    int q = q0 + g*16 + rr;
    size_t idx = ((size_t)(b*S_) + q)*S_ + kbase;
    float4 e = *reinterpret_cast<const float4*>(&attn[idx]);
    e.x *= r4.x; e.y *= r4.y; e.z *= r4.z; e.w *= r4.w;
    *reinterpret_cast<float4*>(&attn[idx]) = e;
  }
}

extern "C" void kernel_launch(void* const* d_in, const int* in_sizes, int n_in,
                              void* d_out, int out_size, void* d_ws, size_t ws_size,
                              hipStream_t stream)
{
  (void)in_sizes; (void)n_in; (void)out_size;
  const float* X  = (const float*)d_in[0];
  const float* Wq = (const float*)d_in[1];
  const float* Wk = (const float*)d_in[2];
  const float* Wv = (const float*)d_in[3];
  float* out  = (float*)d_out;
  float* attn = out + (size_t)B_*S_*DK_;            // attention output region

  float* ws = (float*)d_ws;
  float* V       = ws;                               // [1048576] f32
  unsigned* cmax = (unsigned*)(ws + 1048576);        // [8192]
  float* rcol    = ws + 1056768;                     // [8192]
  float* colpart = ws + 1064960;                     // [262144]
  unsigned short* Wth = (unsigned short*)(ws + 1327104);  // [3][32][5120] shorts
  unsigned short* Wtl = (unsigned short*)(ws + 1572864);
  unsigned short* Qh  = (unsigned short*)(ws + 1818624);  // [8192][128] shorts each
  unsigned short* Ql  = (unsigned short*)(ws + 2342912);
  unsigned short* Kh  = (unsigned short*)(ws + 2867200);
  unsigned short* Kl  = (unsigned short*)(ws + 3391488);
  const size_t base = 3915776;                       // floats used so far
  float* part    = ws + base;                        // [ns][4][2048][128]

  int ns = 8;
  if(ws_size < (base + (size_t)8*1048576)*sizeof(float)) ns = 4;
  if(ws_size < (base + (size_t)4*1048576)*sizeof(float)) ns = 2;
  if(ws_size < (base + (size_t)2*1048576)*sizeof(float)) ns = 1;

  init_kernel<<<dim3(32), dim3(256), 0, stream>>>(cmax);
  wconv_kernel<<<dim3(32,3), dim3(256), 0, stream>>>(Wq, Wk, Wv, Wth, Wtl);
  qkv_mfma_kernel<<<dim3(256,3), dim3(256), 0, stream>>>(X, Wth, Wtl, Qh, Ql, Kh, Kl, V);
  scores_kernel<<<dim3(32,32,4), dim3(256), 0, stream>>>(Qh, Ql, Kh, Kl, attn, cmax);
  expsum_kernel<<<dim3(8,32,4), dim3(256), 0, stream>>>(attn, cmax, colpart);
  colreduce_kernel<<<dim3(32), dim3(256), 0, stream>>>(colpart, rcol);
  vscale_kernel<<<dim3(1024), dim3(256), 0, stream>>>(V, rcol);
  pv_kernel<<<dim3(32,ns,4), dim3(256), 0, stream>>>(attn, V, part, ns);
  pvreduce_kernel<<<dim3(1024), dim3(256), 0, stream>>>(part, out, ns);
  attnnorm_kernel<<<dim3(8,32,4), dim3(256), 0, stream>>>(attn, rcol);
}

// Round 13
// 118.484 us; speedup vs baseline: 2.8755x; 1.7049x over previous
//
#include <hip/hip_runtime.h>
#include <math.h>
#include <stdint.h>

#define B_ 4
#define S_ 2048
#define DM_ 1024
#define DK_ 128

static constexpr float SCALE = 0.08838834764831845f; // 1/sqrt(128)

typedef __attribute__((ext_vector_type(8))) short short8;
typedef __attribute__((ext_vector_type(4))) float f32x4;
typedef __attribute__((ext_vector_type(4))) unsigned short us4;

__device__ __forceinline__ unsigned enc_f32(float f){
  unsigned u = __float_as_uint(f);
  return (u & 0x80000000u) ? ~u : (u | 0x80000000u);
}
__device__ __forceinline__ float dec_f32(unsigned u){
  unsigned v = (u & 0x80000000u) ? (u & 0x7FFFFFFFu) : ~u;
  return __uint_as_float(v);
}
__device__ __forceinline__ float f4get(const float4& v, int i){
  switch(i){ case 0: return v.x; case 1: return v.y; case 2: return v.z; default: return v.w; }
}
__device__ __forceinline__ unsigned short bf16rne(float f){
  unsigned u = __float_as_uint(f);
  unsigned r = (u + 0x7FFFu + ((u>>16)&1u)) >> 16;
  return (unsigned short)r;
}
__device__ __forceinline__ float bf16tof(unsigned short h){
  return __uint_as_float((unsigned)h << 16);
}
// async global->LDS, 16B per lane; LDS dest = wave-uniform base + lane*16
__device__ __forceinline__ void gload16(const void* g, void* l){
  __builtin_amdgcn_global_load_lds(
      (const __attribute__((address_space(1))) void*)g,
      (__attribute__((address_space(3))) void*)l, 16, 0, 0);
}

// ---- init: column-max to enc(-inf) ----
__global__ __launch_bounds__(256) void init_kernel(unsigned* __restrict__ cmax){
  int i = blockIdx.x*256 + threadIdx.x;
  if(i < B_*S_) cmax[i] = 0x007FFFFFu; // enc(-INF)
}

// ---- W pre-convert: f32 [1024][128] -> bf16 hi/lo, pre-tiled [32 t][col][40] ----
__global__ __launch_bounds__(256) void wconv_kernel(
    const float* __restrict__ Wq, const float* __restrict__ Wk, const float* __restrict__ Wv,
    unsigned short* __restrict__ Wth, unsigned short* __restrict__ Wtl)
{
  const int t = blockIdx.x;       // k-tile 0..31
  const int which = blockIdx.y;   // 0..2
  const float* W = (which==0) ? Wq : ((which==1) ? Wk : Wv);
  const int tid = threadIdx.x;
  const size_t obase = ((size_t)which*32 + t)*5120;
  #pragma unroll
  for(int it=0; it<2; ++it){
    int idx = tid + 256*it;       // 0..511 -> (col, g)
    int col = idx & 127, g = idx >> 7;
    unsigned short hs[8], ls[8];
    #pragma unroll
    for(int j=0;j<8;j++){
      float f = W[(size_t)(t*32 + g*8 + j)*DK_ + col];
      unsigned short h = bf16rne(f);
      hs[j] = h;
      ls[j] = bf16rne(f - bf16tof(h));
    }
    size_t o = obase + (size_t)col*40 + g*8;
    *(us4*)&Wth[o]   = us4{hs[0],hs[1],hs[2],hs[3]};
    *(us4*)&Wth[o+4] = us4{hs[4],hs[5],hs[6],hs[7]};
    *(us4*)&Wtl[o]   = us4{ls[0],ls[1],ls[2],ls[3]};
    *(us4*)&Wtl[o+4] = us4{ls[4],ls[5],ls[6],ls[7]};
  }
}

// ---- QKV GEMM: bf16x3 MFMA. Q,K -> bf16 hi/lo dense; V -> bf16 hi/lo TRANSPOSED [b][d][s] ----
__global__ __launch_bounds__(256) void qkv_mfma_kernel(
    const float* __restrict__ X,
    const unsigned short* __restrict__ Wth, const unsigned short* __restrict__ Wtl,
    unsigned short* __restrict__ Qh, unsigned short* __restrict__ Ql,
    unsigned short* __restrict__ Kh, unsigned short* __restrict__ Kl,
    unsigned short* __restrict__ Vth, unsigned short* __restrict__ Vtl)
{
  // carve: Ah[32][40] 2.5K | Al 2.5K | Bh0 10K | Bh1 10K | Bl0 10K | Bl1 10K = 45KB
  __shared__ __align__(16) unsigned char smem[46080];
  unsigned short* Ah = (unsigned short*)smem;
  unsigned short* Al = (unsigned short*)(smem + 2560);
  const int tid = threadIdx.x;
  const int w = tid >> 6, lane = tid & 63;
  const int which = blockIdx.y;
  const int m0 = blockIdx.x * 32;
  const unsigned char* Wh8 = (const unsigned char*)(Wth + (size_t)which*32*5120);
  const unsigned char* Wl8 = (const unsigned char*)(Wtl + (size_t)which*32*5120);

  const int xrow = tid >> 3, xkq = tid & 7;
  const float* Xg = X + (size_t)(m0 + xrow)*DM_ + xkq*4;
  float4 xv = *reinterpret_cast<const float4*>(Xg);     // tile 0

  #pragma unroll
  for(int ii=0; ii<5; ++ii){
    int i = w + 4*ii;
    const unsigned char* src = (i<10) ? (Wh8 + i*1024) : (Wl8 + (i-10)*1024);
    unsigned dst = (i<10) ? (5120u + i*1024u) : (25600u + (unsigned)(i-10)*1024u);
    gload16(src + lane*16, smem + dst);
  }

  f32x4 acc[4] = {f32x4{0,0,0,0},f32x4{0,0,0,0},f32x4{0,0,0,0},f32x4{0,0,0,0}};
  const int r = w >> 1, c0 = (w & 1)*4;   // wave -> (row-tile, col-tile base)
  const int g = lane >> 4;
  const int aoff = (r*16 + (lane&15))*40 + g*8;
  int buf = 0;
  for(int t=0; t<32; ++t){
    __syncthreads();            // prev readers done; B gloads (cur buf) drained
    {  // write A tile t (hi/lo bf16) from the prefetched float4
      unsigned short h0=bf16rne(xv.x), h1=bf16rne(xv.y), h2=bf16rne(xv.z), h3=bf16rne(xv.w);
      us4 hs = {h0,h1,h2,h3};
      us4 ls = { bf16rne(xv.x - bf16tof(h0)), bf16rne(xv.y - bf16tof(h1)),
                 bf16rne(xv.z - bf16tof(h2)), bf16rne(xv.w - bf16tof(h3)) };
      *(us4*)&Ah[xrow*40 + xkq*4] = hs;
      *(us4*)&Al[xrow*40 + xkq*4] = ls;
    }
    __syncthreads();            // A visible
    if(t+1 < 32){               // issue next B tile + X reg prefetch
      const unsigned char* WhT = Wh8 + (size_t)(t+1)*10240;
      const unsigned char* WlT = Wl8 + (size_t)(t+1)*10240;
      unsigned bhN = (buf^1) ? 15360u : 5120u;
      unsigned blN = (buf^1) ? 35840u : 25600u;
      #pragma unroll
      for(int ii=0; ii<5; ++ii){
        int i = w + 4*ii;
        const unsigned char* src = (i<10) ? (WhT + i*1024) : (WlT + (i-10)*1024);
        unsigned dst = (i<10) ? (bhN + i*1024) : (blN + (unsigned)(i-10)*1024);
        gload16(src + lane*16, smem + dst);
      }
      xv = *reinterpret_cast<const float4*>(Xg + (t+1)*32);
    }
    const unsigned short* Bhc = (const unsigned short*)(smem + (buf ? 15360 : 5120));
    const unsigned short* Blc = (const unsigned short*)(smem + (buf ? 35840 : 25600));
    short8 ah = *(const short8*)&Ah[aoff];
    short8 al = *(const short8*)&Al[aoff];
    #pragma unroll
    for(int c=0;c<4;c++){
      int boff = ((c0+c)*16 + (lane&15))*40 + g*8;
      short8 bh = *(const short8*)&Bhc[boff];
      short8 bl = *(const short8*)&Blc[boff];
      acc[c] = __builtin_amdgcn_mfma_f32_16x16x32_bf16(ah, bh, acc[c], 0, 0, 0);
      acc[c] = __builtin_amdgcn_mfma_f32_16x16x32_bf16(ah, bl, acc[c], 0, 0, 0);
      acc[c] = __builtin_amdgcn_mfma_f32_16x16x32_bf16(al, bh, acc[c], 0, 0, 0);
    }
    buf ^= 1;
  }
  // epilogue: C layout col=lane&15, row=(lane>>4)*4+reg  [verified m89/m91]
  const int b = m0 >> 11;
  const int orow0 = (lane>>4)*4;
  if(which != 2){
    unsigned short* Oh = (which==0) ? Qh : Kh;
    unsigned short* Ol = (which==0) ? Ql : Kl;
    #pragma unroll
    for(int c=0;c<4;c++){
      int col = (c0+c)*16 + (lane&15);
      #pragma unroll
      for(int j=0;j<4;j++){
        float f = acc[c][j];
        unsigned short h = bf16rne(f);
        unsigned short lo = bf16rne(f - bf16tof(h));
        size_t o = (size_t)(m0 + r*16 + orow0 + j)*DK_ + col;
        Oh[o] = h; Ol[o] = lo;
      }
    }
  } else {
    // V: transpose through LDS, store bf16 hi/lo as Vt[b][d][s]
    __syncthreads();
    float* Tmp = (float*)smem;                 // [32][133] = 17KB
    #pragma unroll
    for(int c=0;c<4;c++){
      int col = (c0+c)*16 + (lane&15);
      #pragma unroll
      for(int j=0;j<4;j++)
        Tmp[(r*16 + orow0 + j)*133 + col] = acc[c][j];
    }
    __syncthreads();
    const int s0 = m0 & (S_-1);
    #pragma unroll
    for(int l2=0;l2<16;l2++){
      int p = tid + 256*l2;                    // 4096 elems: 128 d x 32 rows
      int d = p >> 5, rr = p & 31;
      float f = Tmp[rr*133 + d];
      unsigned short h = bf16rne(f);
      Vth[(size_t)(b*DK_ + d)*S_ + s0 + rr] = h;
      Vtl[(size_t)(b*DK_ + d)*S_ + s0 + rr] = bf16rne(f - bf16tof(h));
    }
  }
}

// ---- scores via bf16x3 MFMA: raw s (masked=0) -> attn; column max ----
__global__ __launch_bounds__(256) void scores_kernel(
    const unsigned short* __restrict__ Qh, const unsigned short* __restrict__ Ql,
    const unsigned short* __restrict__ Kh, const unsigned short* __restrict__ Kl,
    float* __restrict__ attn, unsigned* __restrict__ cmax)
{
  const int tj = blockIdx.x, ti = blockIdx.y, b = blockIdx.z;
  const int tid = threadIdx.x;
  const int q0 = ti*64, k0 = tj*64;
  if(tj > ti){                                 // upper triangle: zero-fill tile
    float4 z = {0.f,0.f,0.f,0.f};
    #pragma unroll
    for(int l=0;l<4;l++){
      int p = tid + 256*l;
      int r = p >> 4, c = (p & 15) << 2;
      *reinterpret_cast<float4*>(&attn[((size_t)(b*S_) + q0 + r)*S_ + k0 + c]) = z;
    }
    return;
  }
  __shared__ __align__(16) unsigned short sm[18432];   // 4 x [64][72]
  __shared__ float cred[16][64];
  unsigned short* Qhs = sm;
  unsigned short* Qls = sm + 4608;
  unsigned short* Khs = sm + 9216;
  unsigned short* Kls = sm + 13824;
  const int w = tid >> 6, lane = tid & 63, l15 = lane & 15, g = lane >> 4;
  f32x4 acc[4] = {f32x4{0,0,0,0},f32x4{0,0,0,0},f32x4{0,0,0,0},f32x4{0,0,0,0}};
  for(int kh=0; kh<2; ++kh){
    __syncthreads();                           // prev compute readers done
    #pragma unroll
    for(int l=0;l<2;l++){                      // stage 4 tiles (this K-half)
      int p = tid + 256*l;
      int row = p >> 3, cc = p & 7;
      size_t gq = (size_t)(b*S_ + q0 + row)*DK_ + kh*64 + cc*8;
      size_t gk = (size_t)(b*S_ + k0 + row)*DK_ + kh*64 + cc*8;
      int lo_ = row*72 + cc*8;
      *(short8*)&Qhs[lo_] = *(const short8*)&Qh[gq];
      *(short8*)&Qls[lo_] = *(const short8*)&Ql[gq];
      *(short8*)&Khs[lo_] = *(const short8*)&Kh[gk];
      *(short8*)&Kls[lo_] = *(const short8*)&Kl[gk];
    }
    __syncthreads();
    #pragma unroll
    for(int ks=0; ks<2; ++ks){                 // 2 x K=32 per half
      int ao = (w*16 + l15)*72 + ks*32 + g*8;
      short8 ah = *(const short8*)&Qhs[ao];
      short8 al = *(const short8*)&Qls[ao];
      #pragma unroll
      for(int c=0;c<4;c++){
        int bo = (c*16 + l15)*72 + ks*32 + g*8;
        short8 bh = *(const short8*)&Khs[bo];
        short8 bl = *(const short8*)&Kls[bo];
        acc[c] = __builtin_amdgcn_mfma_f32_16x16x32_bf16(ah, bh, acc[c], 0, 0, 0);
        acc[c] = __builtin_amdgcn_mfma_f32_16x16x32_bf16(ah, bl, acc[c], 0, 0, 0);
        acc[c] = __builtin_amdgcn_mfma_f32_16x16x32_bf16(al, bh, acc[c], 0, 0, 0);
      }
    }
  }
  const bool full = (ti > tj);
  const int qbase = q0 + w*16 + g*4;
  #pragma unroll
  for(int c=0;c<4;c++){
    int kcol = k0 + c*16 + l15;
    float cm = -INFINITY;
    #pragma unroll
    for(int j=0;j<4;j++){
      int q = qbase + j;
      float s = acc[c][j]*SCALE;
      bool valid = full || (q >= kcol);
      attn[((size_t)(b*S_) + q)*S_ + kcol] = valid ? s : 0.f;
      if(valid) cm = fmaxf(cm, s);
    }
    cred[w*4 + g][c*16 + l15] = cm;
  }
  __syncthreads();
  if(tid < 64){
    float m = cred[0][tid];
    #pragma unroll
    for(int gg=1;gg<16;gg++) m = fmaxf(m, cred[gg][tid]);
    atomicMax(&cmax[b*S_ + k0 + tid], enc_f32(m));
  }
}

// ---- exp + per-column partial sums (READ-ONLY: no store; pv recomputes p) ----
__global__ __launch_bounds__(256) void expsum_kernel(
    const float* __restrict__ attn, const unsigned* __restrict__ cmax,
    float* __restrict__ colpart)
{
  const int cj = blockIdx.x, ti = blockIdx.y, b = blockIdx.z;
  if(ti < 4*cj) return;                        // fully masked block
  __shared__ float part[4][256];
  const int tid = threadIdx.x;
  const int c4 = tid & 63, g = tid >> 6;
  const int q0 = ti*64, k0 = cj*256;
  const int kbase = k0 + c4*4;
  float mc[4];
  #pragma unroll
  for(int j=0;j<4;j++) mc[j] = dec_f32(cmax[b*S_ + kbase + j]);
  float sum[4] = {0.f,0.f,0.f,0.f};
  #pragma unroll 4
  for(int rr=0;rr<16;rr++){
    int q = q0 + g*16 + rr;
    size_t idx = ((size_t)(b*S_) + q)*S_ + kbase;
    float4 sv = *reinterpret_cast<const float4*>(&attn[idx]);
    sum[0] += (q >= kbase+0) ? __expf(sv.x - mc[0]) : 0.f;
    sum[1] += (q >= kbase+1) ? __expf(sv.y - mc[1]) : 0.f;
    sum[2] += (q >= kbase+2) ? __expf(sv.z - mc[2]) : 0.f;
    sum[3] += (q >= kbase+3) ? __expf(sv.w - mc[3]) : 0.f;
  }
  #pragma unroll
  for(int j=0;j<4;j++) part[g][c4*4+j] = sum[j];
  __syncthreads();
  {
    int k = k0 + tid;
    float tot = ((part[0][tid] + part[1][tid]) + part[2][tid]) + part[3][tid];
    colpart[((size_t)(b*S_) + k)*32 + ti] = tot;
  }
}

// ---- column reduce in fixed order -> reciprocal sums ----
__global__ __launch_bounds__(256) void colreduce_kernel(
    const float* __restrict__ colpart, float* __restrict__ rcol)
{
  int i = blockIdx.x*256 + threadIdx.x;  // 0..8191 = b*S + k
  if(i >= B_*S_) return;
  int k = i & (S_-1);
  int t0 = k >> 6;
  float s = 0.f;
  for(int t=t0; t<32; t++) s += colpart[(size_t)i*32 + t];
  rcol[i] = 1.0f / s;
}

// ---- fused PV (bf16x3 MFMA): p=exp(s-m)*rcol written to attn in place; partials out ----
__global__ __launch_bounds__(256) void pv_kernel(
    float* __restrict__ attn, const unsigned* __restrict__ cmax,
    const float* __restrict__ rcol,
    const unsigned short* __restrict__ Vth, const unsigned short* __restrict__ Vtl,
    float* __restrict__ part, int ns)
{
  __shared__ __align__(16) unsigned short sm[27648];  // Ah,Al [64][72]; Vh,Vl [128][72] = 54KB
  unsigned short* Ahs = sm;
  unsigned short* Als = sm + 4608;
  unsigned short* Vhs = sm + 9216;
  unsigned short* Vls = sm + 18432;
  const int b = blockIdx.z, tid = threadIdx.x;
  const int sp = blockIdx.y;
  const int w = tid >> 6, lane = tid & 63, l15 = lane & 15, g = lane >> 4;
  const int t = 31 - (int)blockIdx.x;              // heavy tiles first
  const int q0 = t*64;
  const int nch = t + 1;
  const int lo = (sp*nch)/ns, hi = ((sp+1)*nch)/ns;
  f32x4 acc[8] = {f32x4{0,0,0,0},f32x4{0,0,0,0},f32x4{0,0,0,0},f32x4{0,0,0,0},
                  f32x4{0,0,0,0},f32x4{0,0,0,0},f32x4{0,0,0,0},f32x4{0,0,0,0}};
  const int er = tid >> 4, ekq = (tid & 15) << 2;  // E quad: rows rr*16+er, cols ekq..+3
  for(int ch=lo; ch<hi; ++ch){
    const int k0c = ch*64;
    uint4 mu = *reinterpret_cast<const uint4*>(&cmax[b*S_ + k0c + ekq]);
    float4 r4 = *reinterpret_cast<const float4*>(&rcol[b*S_ + k0c + ekq]);
    float mc0 = dec_f32(mu.x), mc1 = dec_f32(mu.y), mc2 = dec_f32(mu.z), mc3 = dec_f32(mu.w);
    const bool diag = (ch == t);
    __syncthreads();                               // prev MFMA readers done
    #pragma unroll
    for(int rr=0; rr<4; ++rr){
      int row = rr*16 + er;
      size_t ea = ((size_t)(b*S_) + q0 + row)*S_ + k0c + ekq;
      float4 sv = *reinterpret_cast<const float4*>(&attn[ea]);
      float p0 = __expf(sv.x - mc0)*r4.x;
      float p1 = __expf(sv.y - mc1)*r4.y;
      float p2 = __expf(sv.z - mc2)*r4.z;
      float p3 = __expf(sv.w - mc3)*r4.w;
      if(diag){                                    // q>=k  <=>  row>=kc (q0==k0c)
        p0 = (row >= ekq+0) ? p0 : 0.f;
        p1 = (row >= ekq+1) ? p1 : 0.f;
        p2 = (row >= ekq+2) ? p2 : 0.f;
        p3 = (row >= ekq+3) ? p3 : 0.f;
      }
      float4 pv4 = {p0,p1,p2,p3};
      *reinterpret_cast<float4*>(&attn[ea]) = pv4; // normalized attention (final output)
      unsigned short h0=bf16rne(p0), h1=bf16rne(p1), h2=bf16rne(p2), h3=bf16rne(p3);
      *(us4*)&Ahs[row*72 + ekq] = us4{h0,h1,h2,h3};
      *(us4*)&Als[row*72 + ekq] = us4{ bf16rne(p0-bf16tof(h0)), bf16rne(p1-bf16tof(h1)),
                                       bf16rne(p2-bf16tof(h2)), bf16rne(p3-bf16tof(h3)) };
    }
    #pragma unroll
    for(int v=0; v<4; ++v){                        // V stage: [128 d][64 k] hi/lo (1024 chunks)
      int idx = v*256 + tid;
      int d = idx >> 3, c8 = (idx & 7) << 3;
      size_t ga = (size_t)(b*DK_ + d)*S_ + k0c + c8;
      *(short8*)&Vhs[d*72 + c8] = *(const short8*)&Vth[ga];
      *(short8*)&Vls[d*72 + c8] = *(const short8*)&Vtl[ga];
    }
    __syncthreads();
    #pragma unroll
    for(int ks=0; ks<2; ++ks){
      int ao = (w*16 + l15)*72 + ks*32 + g*8;
      short8 ah = *(const short8*)&Ahs[ao];
      short8 al = *(const short8*)&Als[ao];
      #pragma unroll
      for(int c=0;c<8;c++){
        int bo = (c*16 + l15)*72 + ks*32 + g*8;
        short8 bh = *(const short8*)&Vhs[bo];
        short8 bl = *(const short8*)&Vls[bo];
        acc[c] = __builtin_amdgcn_mfma_f32_16x16x32_bf16(ah, bh, acc[c], 0, 0, 0);
        acc[c] = __builtin_amdgcn_mfma_f32_16x16x32_bf16(ah, bl, acc[c], 0, 0, 0);
        acc[c] = __builtin_amdgcn_mfma_f32_16x16x32_bf16(al, bh, acc[c], 0, 0, 0);
      }
    }
  }
  float* pout = part + (((size_t)(sp*B_ + b))*S_ + q0)*DK_;   // 64 x 128 region
  #pragma unroll
  for(int c=0;c<8;c++){
    #pragma unroll
    for(int j=0;j<4;j++){
      int qrow = w*16 + g*4 + j;
      pout[(size_t)qrow*DK_ + c*16 + l15] = acc[c][j];
    }
  }
}

// ---- sum split-K partials in fixed order ----
__global__ __launch_bounds__(256) void pvreduce_kernel(
    const float* __restrict__ part, float* __restrict__ out, int ns)
{
  const int N4 = (B_*S_*DK_)/4;   // 262144 float4
  int i = blockIdx.x*256 + threadIdx.x;
  if(i >= N4) return;
  const float4* p = reinterpret_cast<const float4*>(part);
  float4 a = p[i];
  for(int s=1; s<ns; ++s){
    float4 q = p[(size_t)s*N4 + i];
    a.x += q.x; a.y += q.y; a.z += q.z; a.w += q.w;
  }
  reinterpret_cast<float4*>(out)[i] = a;
}

extern "C" void kernel_launch(void* const* d_in, const int* in_sizes, int n_in,
                              void* d_out, int out_size, void* d_ws, size_t ws_size,
                              hipStream_t stream)
{
  (void)in_sizes; (void)n_in; (void)out_size;
  const float* X  = (const float*)d_in[0];
  const float* Wq = (const float*)d_in[1];
  const float* Wk = (const float*)d_in[2];
  const float* Wv = (const float*)d_in[3];
  float* out  = (float*)d_out;
  float* attn = out + (size_t)B_*S_*DK_;            // attention output region

  float* ws = (float*)d_ws;
  unsigned* cmax = (unsigned*)ws;                    // [8192]
  float* rcol    = ws + 8192;                        // [8192]
  float* colpart = ws + 16384;                       // [262144]
  unsigned short* Wth = (unsigned short*)(ws + 278528);   // [3][32][5120] shorts
  unsigned short* Wtl = (unsigned short*)(ws + 524288);
  unsigned short* Qh  = (unsigned short*)(ws + 770048);   // [8192][128] shorts each
  unsigned short* Ql  = (unsigned short*)(ws + 1294336);
  unsigned short* Kh  = (unsigned short*)(ws + 1818624);
  unsigned short* Kl  = (unsigned short*)(ws + 2342912);
  unsigned short* Vth = (unsigned short*)(ws + 2867200);  // [4][128][2048] shorts each
  unsigned short* Vtl = (unsigned short*)(ws + 3391488);
  const size_t base = 3915776;                       // floats used so far
  float* part    = ws + base;                        // [ns][4][2048][128]

  int ns = 4;
  if(ws_size < (base + (size_t)4*1048576)*sizeof(float)) ns = 2;
  if(ws_size < (base + (size_t)2*1048576)*sizeof(float)) ns = 1;

  init_kernel<<<dim3(32), dim3(256), 0, stream>>>(cmax);
  wconv_kernel<<<dim3(32,3), dim3(256), 0, stream>>>(Wq, Wk, Wv, Wth, Wtl);
  qkv_mfma_kernel<<<dim3(256,3), dim3(256), 0, stream>>>(X, Wth, Wtl, Qh, Ql, Kh, Kl, Vth, Vtl);
  scores_kernel<<<dim3(32,32,4), dim3(256), 0, stream>>>(Qh, Ql, Kh, Kl, attn, cmax);
  expsum_kernel<<<dim3(8,32,4), dim3(256), 0, stream>>>(attn, cmax, colpart);
  colreduce_kernel<<<dim3(32), dim3(256), 0, stream>>>(colpart, rcol);
  pv_kernel<<<dim3(32,ns,4), dim3(256), 0, stream>>>(attn, cmax, rcol, Vth, Vtl, part, ns);
  pvreduce_kernel<<<dim3(1024), dim3(256), 0, stream>>>(part, out, ns);
}